// Round 9
// baseline (369.788 us; speedup 1.0000x reference)
//
#include <hip/hip_runtime.h>
#include <hip/hip_bf16.h>
#include <math.h>

typedef __hip_bfloat16 bf16;
typedef short s8v __attribute__((ext_vector_type(8)));
typedef short s4v __attribute__((ext_vector_type(4)));
typedef float f4v __attribute__((ext_vector_type(4)));

__device__ __forceinline__ float b2f(bf16 x) { return __bfloat162float(x); }
__device__ __forceinline__ bf16 f2b(float x) { return __float2bfloat16(x); }
__device__ __forceinline__ f4v mfma16(s8v a, s8v b, f4v c) {
    return __builtin_amdgcn_mfma_f32_16x16x32_bf16(a, b, c, 0, 0, 0);
}
__device__ __forceinline__ void async16(const bf16* g, bf16* l) {
    __builtin_amdgcn_global_load_lds(
        (const __attribute__((address_space(1))) void*)g,
        (__attribute__((address_space(3))) void*)l, 16, 0, 0);
}

constexpr int Bn = 4, Tn = 2048, Dn = 1024, KDn = 512, VDn = 1024;
constexpr int Hn = 4, Mn = 64, HKn = 128, HVn = 256;
constexpr int BT = Bn * Tn;

// ---------------------------------------------------------------------------
__global__ __launch_bounds__(256) void probe_dtype_kernel(
    const void* __restrict__ x, int* __restrict__ flag)
{
    const bf16* xb = (const bf16*)x;
    float mx = 0.f;
    for (int i = threadIdx.x; i < 4096; i += 256) {
        float v = fabsf(b2f(xb[i]));
        if (isnan(v)) v = 1e30f;
        mx = fmaxf(mx, v);
    }
    __shared__ float red[256];
    red[threadIdx.x] = mx;
    __syncthreads();
    for (int s = 128; s > 0; s >>= 1) {
        if (threadIdx.x < s) red[threadIdx.x] = fmaxf(red[threadIdx.x], red[threadIdx.x + s]);
        __syncthreads();
    }
    if (threadIdx.x == 0) flag[0] = (red[0] > 1e6f) ? 1 : 0;
}

// ---------------------------------------------------------------------------
// All input conversions in ONE launch (unchanged from r7).
// ---------------------------------------------------------------------------
__global__ __launch_bounds__(256) void convert_fused(
    const void* __restrict__ x,
    const void* s0, const void* s1, const void* s2, const void* s3,
    const void* s4, const void* s5,
    const void* sq, const void* sk, const void* sv, const void* sg,
    bf16* __restrict__ Xb,
    bf16* d0, bf16* d1, bf16* d2, bf16* d3, bf16* d4, bf16* d5,
    bf16* __restrict__ qd, bf16* __restrict__ kd,
    bf16* __restrict__ vd, bf16* __restrict__ gd,
    const int* __restrict__ flag)
{
    __shared__ bf16 tile[64 * 72];
    const int nb = blockIdx.x, tid = threadIdx.x;
    const int is32 = flag[0];
    if (nb < 8192) {
        int i0 = (nb * 256 + tid) * 4;
#pragma unroll
        for (int j = 0; j < 4; j++) {
            int i = i0 + j;
            if (i < BT * Dn)
                Xb[i] = is32 ? f2b(((const float*)x)[i]) : ((const bf16*)x)[i];
        }
    } else if (nb == 8192) {
        for (int i = tid; i < 8448; i += 256) {
            const void* s; bf16* d; int l;
            if (i < 2048)      { s = sq; d = qd; l = i; }
            else if (i < 4096) { s = sk; d = kd; l = i - 2048; }
            else if (i < 8192) { s = sv; d = vd; l = i - 4096; }
            else               { s = sg; d = gd; l = i - 8192; }
            d[l] = is32 ? f2b(((const float*)s)[l]) : ((const bf16*)s)[l];
        }
    } else {
        int nb2 = nb - 8193;
        const void* src; bf16* dst; int K, N, loc;
        if (nb2 < 128)       { src = s0; dst = d0; K = 1024; N = 512;  loc = nb2; }
        else if (nb2 < 256)  { src = s1; dst = d1; K = 1024; N = 512;  loc = nb2 - 128; }
        else if (nb2 < 512)  { src = s2; dst = d2; K = 1024; N = 1024; loc = nb2 - 256; }
        else if (nb2 < 576)  { src = s3; dst = d3; K = 1024; N = 256;  loc = nb2 - 512; }
        else if (nb2 < 832)  { src = s4; dst = d4; K = 1024; N = 1024; loc = nb2 - 576; }
        else                 { src = s5; dst = d5; K = 1024; N = 1024; loc = nb2 - 832; }
        int nt = N >> 6;
        int n0 = (loc % nt) * 64, k0 = (loc / nt) * 64;
        int r = tid >> 2, seg = (tid & 3) * 16;
#pragma unroll
        for (int i = 0; i < 16; i++) {
            size_t gi = (size_t)(k0 + r) * N + n0 + seg + i;
            float v = is32 ? ((const float*)src)[gi] : b2f(((const bf16*)src)[gi]);
            tile[r * 72 + seg + i] = f2b(v);
        }
        __syncthreads();
        bf16 tmp[16];
#pragma unroll
        for (int i = 0; i < 16; i++) tmp[i] = tile[(seg + i) * 72 + r];
        size_t o = (size_t)(n0 + r) * K + k0 + seg;
        *(s8v*)&dst[o] = *(s8v*)&tmp[0];
        *(s8v*)&dst[o + 8] = *(s8v*)&tmp[8];
    }
}

// ---------------------------------------------------------------------------
// BM x 256 tile GEMM (BM = MF*32), m201-style 4-phase schedule, with
// VECTORIZED epilogue (LDS-staged, XOR-swizzled, s8v/f4v stores).
// MF=8 (EP4), MF=4 (EP3). Ledger unchanged from r7/r8 (verified).
// ---------------------------------------------------------------------------
template <int EP, int MF>
__global__ __launch_bounds__(512, 2) void gemm256_8p(
    const bf16* __restrict__ A, const bf16* __restrict__ Bt,
    void* __restrict__ Cout, bf16* __restrict__ ETout,
    bf16* __restrict__ aux1, bf16* __restrict__ aux2,
    const int* __restrict__ flag)
{
    constexpr int BM = MF * 32;          // 256 or 128
    constexpr int ASZ = BM * 64;         // A buffer elems (16384 / 8192)
    constexpr int PM = MF / 4;           // m-frags per phase (2 / 1)
    __shared__ alignas(16) bf16 lds[2 * ASZ + 2 * 16384];
    constexpr int K = 1024, NT = 16;
    const int tid = threadIdx.x;
    const int w8 = tid >> 6, lane = tid & 63;
    const int l16 = lane & 15, q2 = lane >> 4;
    const int wr = w8 >> 2, wc = w8 & 3;

    const int bid = blockIdx.x;
    const int xcd = bid & 7, ii = bid >> 3;
    int bx, by;
    if (EP == 4) {
        if (ii < 48) {
            int sc = ii >> 3, rem = ii & 7;
            bx = sc * 2 + (rem & 1);
            by = xcd * 4 + (rem >> 1);
        } else {
            bx = 12;
            by = xcd * 4 + (ii - 48);
        }
    } else {
        bx = ii >> 3;            // 0..3
        by = xcd * 8 + (ii & 7); // 0..63
    }

    const int srow = tid >> 3;
    const int sslot = (tid & 7) ^ (srow & 7);
    const bf16* gA0 = A + (size_t)(by * BM + srow) * K + sslot * 8;
    const bf16* gB0 = Bt + (size_t)(bx * 256 + srow) * K + sslot * 8;
    const int dOff = w8 * 512;

    const int sz0 = ((q2 ^ (l16 & 7))) * 8;
    const int sz1 = (((q2 ^ 4) ^ (l16 & 7))) * 8;
    const int rowA = (wr * (MF * 16) + l16) * 64;

    f4v acc[MF][4];
    f4v z = {0.f, 0.f, 0.f, 0.f};
#pragma unroll
    for (int i = 0; i < MF; i++)
#pragma unroll
        for (int j = 0; j < 4; j++) acc[i][j] = z;

    // prologue: B(0) 4, A(0) MF/2, B(1) 4
#pragma unroll
    for (int g = 0; g < 4; ++g)
        async16(gB0 + (size_t)g * 64 * K, &lds[2 * ASZ] + g * 4096 + dOff);
#pragma unroll
    for (int g = 0; g < MF / 2; ++g)
        async16(gA0 + (size_t)g * 64 * K, &lds[0] + g * 4096 + dOff);
#pragma unroll
    for (int g = 0; g < 4; ++g)
        async16(gB0 + (size_t)g * 64 * K + 64, &lds[2 * ASZ + 16384] + g * 4096 + dOff);
    asm volatile("s_waitcnt vmcnt(4)" ::: "memory");
    __builtin_amdgcn_s_barrier();

    for (int t = 0; t < NT; ++t) {
        const int da = t & 1;
        const bf16* bufA = &lds[da * ASZ];
        const bf16* bufB = &lds[2 * ASZ + da * 16384];
        bf16* stA = &lds[(da ^ 1) * ASZ];
        bf16* stB = &lds[2 * ASZ + da * 16384];
        const int tA = (t + 1 < NT) ? (t + 1) : (NT - 1);
        const int tB = (t + 2 < NT) ? (t + 2) : (NT - 1);
        s8v breg[4][2];
#pragma unroll
        for (int q = 0; q < 4; ++q) {
            if (q == 0) {
#pragma unroll
                for (int ni = 0; ni < 4; ++ni) {
                    int rb = (wc * 64 + ni * 16 + l16) * 64;
                    breg[ni][0] = *(const s8v*)(bufB + rb + sz0);
                    breg[ni][1] = *(const s8v*)(bufB + rb + sz1);
                }
            }
            s8v aq[PM][2];
#pragma unroll
            for (int m = 0; m < PM; ++m) {
                int ra = rowA + (q * PM + m) * 1024;
                aq[m][0] = *(const s8v*)(bufA + ra + sz0);
                aq[m][1] = *(const s8v*)(bufA + ra + sz1);
            }
            if (q == 0) {
#pragma unroll
                for (int g = 0; g < MF / 2; ++g)
                    async16(gA0 + (size_t)tA * 64 + (size_t)g * 64 * K,
                            stA + g * 4096 + dOff);
            } else if (q == 1) {
#pragma unroll
                for (int g = 0; g < 2; ++g)
                    async16(gB0 + (size_t)tB * 64 + (size_t)g * 64 * K,
                            stB + g * 4096 + dOff);
            } else if (q == 2) {
#pragma unroll
                for (int g = 2; g < 4; ++g)
                    async16(gB0 + (size_t)tB * 64 + (size_t)g * 64 * K,
                            stB + g * 4096 + dOff);
            } else {
                asm volatile("s_waitcnt vmcnt(4)" ::: "memory");
            }
            __builtin_amdgcn_s_barrier();
            asm volatile("s_waitcnt lgkmcnt(0)" ::: "memory");
            __builtin_amdgcn_sched_barrier(0);
            __builtin_amdgcn_s_setprio(1);
#pragma unroll
            for (int kq = 0; kq < 2; ++kq)
#pragma unroll
                for (int m = 0; m < PM; ++m)
#pragma unroll
                    for (int ni = 0; ni < 4; ++ni)
                        acc[q * PM + m][ni] =
                            mfma16(aq[m][kq], breg[ni][kq], acc[q * PM + m][ni]);
            __builtin_amdgcn_s_setprio(0);
            __builtin_amdgcn_s_barrier();
        }
    }
    asm volatile("s_waitcnt vmcnt(0)" ::: "memory");
    __builtin_amdgcn_s_barrier();   // all DMA landed, all LDS reads done

    // ---- vectorized epilogue (LDS staged) ----
    if (EP == 4 && bx < 12) {
        // stage bf16 [256][256], group-of-8 XOR swizzle
        bf16* ct = lds;
#pragma unroll
        for (int mi = 0; mi < MF; ++mi)
#pragma unroll
            for (int ni = 0; ni < 4; ++ni)
#pragma unroll
                for (int r = 0; r < 4; ++r) {
                    int row = wr * 128 + mi * 16 + q2 * 4 + r;
                    int col = wc * 64 + ni * 16 + l16;
                    int g = col >> 3;
                    ct[row * 256 + ((g ^ (row & 7)) << 3) + (col & 7)]
                        = f2b(acc[mi][ni][r]);
                }
        __builtin_amdgcn_s_barrier();
        bf16* dst = (bx < 4) ? (bf16*)Cout : (bx < 8 ? aux1 : aux2);
        const int cb = (bx < 4) ? 0 : (bx < 8 ? 1024 : 2048);
        const int rl = tid >> 1, half = tid & 1;
        size_t go = (size_t)(by * 256 + rl) * 1024 + bx * 256 - cb + half * 128;
#pragma unroll
        for (int gi = 0; gi < 16; ++gi) {
            int g = half * 16 + gi;
            s8v v = *(const s8v*)&ct[rl * 256 + ((g ^ (rl & 7)) << 3)];
            *(s8v*)&dst[go + gi * 8] = v;
        }
    } else if (EP == 4) {
        // bx == 12: ET transposed + exp(clip), f32 staged in 2 passes of 128 rows
        float* cf = (float*)lds;   // 128 x 256 f32 = 128 KiB
        const int b_ = by >> 3;
        const int tbase = (by & 7) * 256;
#pragma unroll
        for (int p = 0; p < 2; ++p) {
            if (wr == p) {
#pragma unroll
                for (int mi = 0; mi < MF; ++mi)
#pragma unroll
                    for (int ni = 0; ni < 4; ++ni)
#pragma unroll
                        for (int r = 0; r < 4; ++r) {
                            int row = mi * 16 + q2 * 4 + r;       // 0..127
                            int col = wc * 64 + ni * 16 + l16;
                            int gc = col >> 2;
                            cf[row * 256 + ((gc ^ (row & 7)) << 2) + (col & 3)]
                                = acc[mi][ni][r];
                        }
            }
            __builtin_amdgcn_s_barrier();
            const int c = tid >> 1, rh = (tid & 1) * 64;
            const int h_ = c >> 6, m_ = c & 63;
            const int gc = c >> 2, wi = c & 3;
            bf16* orow = ETout + ((size_t)((b_ * 4 + h_) * 64 + m_)) * 2048
                         + tbase + p * 128 + rh;
#pragma unroll
            for (int j8 = 0; j8 < 8; ++j8) {
                alignas(16) bf16 ob[8];
#pragma unroll
                for (int i = 0; i < 8; ++i) {
                    int row = rh + j8 * 8 + i;
                    float v = cf[row * 256 + ((gc ^ (row & 7)) << 2) + wi];
                    float cl = fminf(32.f, fmaxf(-32.f, v));
                    ob[i] = f2b(expf(cl));
                }
                *(s8v*)&orow[j8 * 8] = *(s8v*)ob;
            }
            __builtin_amdgcn_s_barrier();
        }
    } else {
        // EP == 3: f32 staged in 2 passes of 64 rows; dyn f32 or bf16 out
        float* cf = (float*)lds;   // 64 x 256 f32 = 64 KiB (fits 96 KiB)
        const int dyn = flag[0];
#pragma unroll
        for (int p = 0; p < 2; ++p) {
            if (wr == p) {
#pragma unroll
                for (int mi = 0; mi < MF; ++mi)
#pragma unroll
                    for (int ni = 0; ni < 4; ++ni)
#pragma unroll
                        for (int r = 0; r < 4; ++r) {
                            int row = mi * 16 + q2 * 4 + r;       // 0..63
                            int col = wc * 64 + ni * 16 + l16;
                            int gc = col >> 2;
                            cf[row * 256 + ((gc ^ (row & 7)) << 2) + (col & 3)]
                                = acc[mi][ni][r];
                        }
            }
            __builtin_amdgcn_s_barrier();
            const int rl = tid >> 3, cb8 = (tid & 7) * 32;
            size_t go = (size_t)(by * 128 + p * 64 + rl) * 1024 + bx * 256 + cb8;
#pragma unroll
            for (int gi = 0; gi < 8; ++gi) {
                int gc = (cb8 >> 2) + gi;
                f4v v = *(const f4v*)&cf[rl * 256 + ((gc ^ (rl & 7)) << 2)];
                if (dyn) {
                    *(f4v*)&((float*)Cout)[go + gi * 4] = v;
                } else {
                    alignas(8) bf16 ob[4];
#pragma unroll
                    for (int i = 0; i < 4; ++i) ob[i] = f2b(v[i]);
                    *(s4v*)&((bf16*)Cout)[go + gi * 4] = *(s4v*)ob;
                }
            }
            __builtin_amdgcn_s_barrier();
        }
    }
}

// ---------------------------------------------------------------------------
// Merged conv kernel: nb<2048 -> v (conv+silu -> VT, transposed);
// nb in [2048,2560) -> q (vectorized conv+silu+rope -> Qb);
// nb in [2560,3072) -> k (conv+silu+rope -> KTb, transposed).
// No aliasing: Qb/KTb live over dead Xb, vpre untouched by qk branch.
// ---------------------------------------------------------------------------
__global__ __launch_bounds__(256) void conv_all2_kernel(
    const bf16* __restrict__ qkpre, const bf16* __restrict__ vpre,
    const bf16* __restrict__ qw, const bf16* __restrict__ kw,
    const bf16* __restrict__ vw,
    bf16* __restrict__ Qb, bf16* __restrict__ KT, bf16* __restrict__ VT)
{
    __shared__ bf16 tile[128 * 72];
    const int nb = blockIdx.x, tid = threadIdx.x;
    if (nb < 2048) {
        int c0 = (nb & 15) * 64, t0 = ((nb >> 4) & 31) * 64, b = nb >> 9;
        int row = tid >> 2, seg = (tid & 3) * 16;
        float y[16];
#pragma unroll
        for (int i = 0; i < 16; i++) y[i] = 0.f;
#pragma unroll
        for (int j = 0; j < 4; j++) {
            int tt = t0 + row - 3 + j;
            if (tt >= 0) {
                const bf16* p = &vpre[(size_t)(b * Tn + tt) * VDn + c0 + seg];
#pragma unroll
                for (int i = 0; i < 16; i++)
                    y[i] += b2f(p[i]) * b2f(vw[(c0 + seg + i) * 4 + j]);
            }
        }
#pragma unroll
        for (int i = 0; i < 16; i++) {
            float v = y[i] / (1.f + expf(-y[i]));
            tile[row * 72 + seg + i] = f2b(v);
        }
        __syncthreads();
        bf16 tmp[16];
#pragma unroll
        for (int i = 0; i < 16; i++) tmp[i] = tile[(seg + i) * 72 + row];
        size_t o = (size_t)(b * 1024 + c0 + row) * 2048 + t0 + seg;
        *(s8v*)&VT[o] = *(s8v*)&tmp[0];
        *(s8v*)&VT[o + 8] = *(s8v*)&tmp[8];
    } else if (nb < 2560) {
        const int nq = nb - 2048;
        const int h = nq & 3, tt = (nq >> 2) & 31, b = nq >> 7;
        const int row = tid >> 2, seg = (tid & 3) * 16;
        const int t = tt * 64 + row;
        const int clo = h * 128 + seg;
        float ylo[16], yhi[16];
#pragma unroll
        for (int i = 0; i < 16; i++) { ylo[i] = 0.f; yhi[i] = 0.f; }
        alignas(16) bf16 wlo[64], whi[64];
#pragma unroll
        for (int c = 0; c < 8; c++) {
            *(s8v*)&wlo[c * 8] = *(const s8v*)&qw[clo * 4 + c * 8];
            *(s8v*)&whi[c * 8] = *(const s8v*)&qw[(clo + 64) * 4 + c * 8];
        }
#pragma unroll
        for (int j = 0; j < 4; j++) {
            int ts = t - 3 + j;
            if (ts >= 0) {
                const bf16* p = &qkpre[(size_t)(b * Tn + ts) * 1024 + clo];
                alignas(16) bf16 xl[16], xh[16];
                *(s8v*)&xl[0] = *(const s8v*)p;
                *(s8v*)&xl[8] = *(const s8v*)(p + 8);
                *(s8v*)&xh[0] = *(const s8v*)(p + 64);
                *(s8v*)&xh[8] = *(const s8v*)(p + 72);
#pragma unroll
                for (int i = 0; i < 16; i++) {
                    ylo[i] += b2f(xl[i]) * b2f(wlo[i * 4 + j]);
                    yhi[i] += b2f(xh[i]) * b2f(whi[i * 4 + j]);
                }
            }
        }
        alignas(16) bf16 olo[16], ohi[16];
#pragma unroll
        for (int i = 0; i < 16; i++) {
            float yl = ylo[i] / (1.f + expf(-ylo[i]));
            float yh = yhi[i] / (1.f + expf(-yhi[i]));
            float invf = exp2f(-(float)(seg + i) * 0.2076205059304601f);
            float th = (float)t * invf;
            float c = cosf(th), s = sinf(th);
            olo[i] = f2b(yl * c - yh * s);
            ohi[i] = f2b(yh * c + yl * s);
        }
        size_t rb = (size_t)(b * Tn + t) * KDn + clo;
        *(s8v*)&Qb[rb] = *(s8v*)&olo[0];
        *(s8v*)&Qb[rb + 8] = *(s8v*)&olo[8];
        *(s8v*)&Qb[rb + 64] = *(s8v*)&ohi[0];
        *(s8v*)&Qb[rb + 72] = *(s8v*)&ohi[8];
    } else {
        int r = nb - 2560;
        const int tt = r & 31, h = (r >> 5) & 3, b = r >> 7;
        const int dp = tid >> 2, tq = tid & 3;
        const int clo = 512 + h * 128 + dp, chi = clo + 64;
        const float w0l = b2f(kw[(h * 128 + dp) * 4 + 0]), w1l = b2f(kw[(h * 128 + dp) * 4 + 1]),
                    w2l = b2f(kw[(h * 128 + dp) * 4 + 2]), w3l = b2f(kw[(h * 128 + dp) * 4 + 3]);
        const float w0h = b2f(kw[(h * 128 + dp + 64) * 4 + 0]), w1h = b2f(kw[(h * 128 + dp + 64) * 4 + 1]),
                    w2h = b2f(kw[(h * 128 + dp + 64) * 4 + 2]), w3h = b2f(kw[(h * 128 + dp + 64) * 4 + 3]);
        const float invf = exp2f(-(float)dp * 0.2076205059304601f);
        float l0 = 0.f, l1 = 0.f, l2 = 0.f, h0 = 0.f, h1 = 0.f, h2 = 0.f;
        int tg0 = tt * 64 + tq * 16;
#pragma unroll
        for (int p = 0; p < 3; p++) {
            int tg = tg0 - 3 + p;
            float xl = 0.f, xh = 0.f;
            if (tg >= 0) {
                size_t rb = (size_t)(b * Tn + tg) * 1024;
                xl = b2f(qkpre[rb + clo]);
                xh = b2f(qkpre[rb + chi]);
            }
            l0 = l1; l1 = l2; l2 = xl;
            h0 = h1; h1 = h2; h2 = xh;
        }
        for (int i = 0; i < 16; i++) {
            int tg = tg0 + i;
            size_t rb = (size_t)(b * Tn + tg) * 1024;
            float xl = b2f(qkpre[rb + clo]);
            float xh = b2f(qkpre[rb + chi]);
            float ylo = l0 * w0l + l1 * w1l + l2 * w2l + xl * w3l;
            float yhi = h0 * w0h + h1 * w1h + h2 * w2h + xh * w3h;
            l0 = l1; l1 = l2; l2 = xl;
            h0 = h1; h1 = h2; h2 = xh;
            ylo = ylo / (1.f + expf(-ylo));
            yhi = yhi / (1.f + expf(-yhi));
            float th = (float)tg * invf;
            float c = cosf(th), s = sinf(th);
            int tl = tq * 16 + i;
            tile[dp * 72 + tl] = f2b(ylo * c - yhi * s);
            tile[(dp + 64) * 72 + tl] = f2b(yhi * c + ylo * s);
        }
        __syncthreads();
#pragma unroll
        for (int c = 0; c < 4; c++) {
            int idx = c * 256 + tid;
            int ch = idx >> 3, t8 = (idx & 7) * 8;
            s8v v = *(s8v*)&tile[ch * 72 + t8];
            *(s8v*)&KT[((size_t)((b * 4 + h) * 128 + ch)) * 2048 + tt * 64 + t8] = v;
        }
    }
}

// ---------------------------------------------------------------------------
// Phase A + cumsum merged (unchanged).
// ---------------------------------------------------------------------------
__global__ __launch_bounds__(256) void tile_state_kernel(
    const bf16* __restrict__ ET, const bf16* __restrict__ KT,
    const bf16* __restrict__ VT,
    bf16* __restrict__ Svp, bf16* __restrict__ HpA, bf16* __restrict__ HpB,
    float* __restrict__ Ccp)
{
    const int tid = threadIdx.x;
    const int w = tid >> 6, lane = tid & 63;
    const int l16 = lane & 15, q = lane >> 4;
    f4v z = {0.f, 0.f, 0.f, 0.f};
    if (blockIdx.x < 512) {
        const int bh = blockIdx.x >> 5, j = blockIdx.x & 31;
        const int b = bh >> 2, h = bh & 3;
        const int j64 = j * 64;
        f4v acc[4][4];
#pragma unroll
        for (int i = 0; i < 4; i++)
#pragma unroll
            for (int jj = 0; jj < 4; jj++) acc[i][jj] = z;
#pragma unroll
        for (int kc = 0; kc < 2; kc++) {
            s8v va[4], eb[4];
#pragma unroll
            for (int vf = 0; vf < 4; vf++)
                va[vf] = *(const s8v*)(VT + (size_t)(b * 1024 + h * 256 + w * 64 + vf * 16 + l16) * 2048
                                       + j64 + kc * 32 + q * 8);
#pragma unroll
            for (int mf = 0; mf < 4; mf++)
                eb[mf] = *(const s8v*)(ET + (size_t)(bh * 64 + mf * 16 + l16) * 2048
                                       + j64 + kc * 32 + q * 8);
#pragma unroll
            for (int vf = 0; vf < 4; vf++)
#pragma unroll
                for (int mf = 0; mf < 4; mf++)
                    acc[vf][mf] = mfma16(va[vf], eb[mf], acc[vf][mf]);
        }
#pragma unroll
        for (int vf = 0; vf < 4; vf++)
#pragma unroll
            for (int mf = 0; mf < 4; mf++)
#pragma unroll
                for (int r = 0; r < 4; r++)
                    Svp[((size_t)((bh * 32 + j) * 256 + w * 64 + vf * 16 + q * 4 + r)) * 64
                        + mf * 16 + l16] = f2b(acc[vf][mf][r]);
    } else if (blockIdx.x < 1024) {
        const int idx = blockIdx.x - 512;
        const int bh = idx >> 5, j = idx & 31;
        const int j64 = j * 64;
        bf16* hp = (bh < 12) ? (HpA + (size_t)bh * 262144)
                             : (HpB + (size_t)(bh - 12) * 262144);
        f4v acc[8];
#pragma unroll
        for (int i = 0; i < 8; i++) acc[i] = z;
#pragma unroll
        for (int kc = 0; kc < 2; kc++) {
            s8v ea = *(const s8v*)(ET + (size_t)(bh * 64 + w * 16 + l16) * 2048
                                   + j64 + kc * 32 + q * 8);
#pragma unroll
            for (int kf = 0; kf < 8; kf++) {
                s8v kb = *(const s8v*)(KT + (size_t)(bh * 128 + kf * 16 + l16) * 2048
                                       + j64 + kc * 32 + q * 8);
                acc[kf] = mfma16(ea, kb, acc[kf]);
            }
        }
#pragma unroll
        for (int kf = 0; kf < 8; kf++)
#pragma unroll
            for (int r = 0; r < 4; r++)
                hp[((size_t)(j64 + w * 16 + q * 4 + r)) * 128 + kf * 16 + l16]
                    = f2b(acc[kf][r]);
    } else {
        int row = (blockIdx.x - 1024) * 4 + w;
        int b = row >> 8, hm = row & 255;
        const bf16* src = ET + (size_t)row * 2048;
        float run = 0.f;
        for (int ch = 0; ch < 32; ch++) {
            if (lane == 0) Ccp[(size_t)(b * 32 + ch) * 256 + hm] = run;
            float v = b2f(src[ch * 64 + lane]);
#pragma unroll
            for (int off = 1; off < 64; off <<= 1) {
                float o = __shfl_up(v, off, 64);
                if (lane >= off) v += o;
            }
            run += __shfl(v, 63, 64);
        }
    }
}

// ---------------------------------------------------------------------------
// Phase B: in-place exclusive prefix over j (unchanged).
// ---------------------------------------------------------------------------
__global__ __launch_bounds__(256) void prefix_state_kernel(
    bf16* __restrict__ Svp, bf16* __restrict__ HpA, bf16* __restrict__ HpB)
{
    if (blockIdx.x < 1024) {
        int gid = blockIdx.x * 256 + threadIdx.x;
        int bh = gid >> 14, e = gid & 16383;
        bf16* p = Svp + (size_t)bh * 524288 + e;
        float run = 0.f;
#pragma unroll 4
        for (int j = 0; j < 32; j++) {
            float x = b2f(p[(size_t)j * 16384]);
            p[(size_t)j * 16384] = f2b(run);
            run += x;
        }
    } else {
        int gid = (blockIdx.x - 1024) * 256 + threadIdx.x;
        int bh = gid >> 13, e = gid & 8191;
        bf16* hp = ((bh < 12) ? (HpA + (size_t)bh * 262144)
                              : (HpB + (size_t)(bh - 12) * 262144)) + e;
        float run = 0.f;
#pragma unroll 4
        for (int j = 0; j < 32; j++) {
            float x = b2f(hp[(size_t)j * 8192]);
            hp[(size_t)j * 8192] = f2b(run);
            run += x;
        }
    }
}

// ---------------------------------------------------------------------------
// Fused attention (unchanged from r8).
// ---------------------------------------------------------------------------
__global__ __launch_bounds__(256) void attn12_mfma(
    const bf16* __restrict__ Q, const bf16* __restrict__ KT,
    const bf16* __restrict__ ET, const float* __restrict__ Ccp,
    const bf16* __restrict__ HpA, const bf16* __restrict__ HpB,
    const bf16* __restrict__ Svp, const bf16* __restrict__ VT,
    const bf16* __restrict__ gate, const bf16* __restrict__ gn,
    bf16* __restrict__ OV)
{
    __shared__ char smem[53760];
    bf16*  Kloc = (bf16*)smem;
    float* Ot   = (float*)smem;
    bf16*  Sl   = (bf16*)(smem + 17408);
    bf16*  Ct   = (bf16*)(smem + 17408);
    bf16*  Etl  = (bf16*)(smem + 17408);
    float* okT  = (float*)(smem + 26624);
    bf16*  Pl   = (bf16*)(smem + 26624);
    bf16*  Ul   = (bf16*)(smem + 43264);
    float* swave= (float*)(smem + 52480);
    float* ssum = (float*)(smem + 53504);
    const int tid = threadIdx.x;
    const int w = tid >> 6, lane = tid & 63;
    const int l16 = lane & 15, q = lane >> 4;
    const int bh = blockIdx.x, b = bh >> 2, h = bh & 3;
    const int j = blockIdx.y, j64 = j * 64;
    f4v z = {0.f, 0.f, 0.f, 0.f};
    const bf16* hp = (bh < 12) ? (HpA + (size_t)bh * 262144)
                               : (HpB + (size_t)(bh - 12) * 262144);

#pragma unroll
    for (int c = 0; c < 4; c++) {
        int idx = c * 256 + tid;
        int kr = idx >> 3, t8 = (idx & 7) * 8;
        alignas(16) bf16 tmp[8];
        *(s8v*)tmp = *(const s8v*)&KT[((size_t)(bh * 128 + kr)) * 2048 + j64 + t8];
#pragma unroll
        for (int i = 0; i < 8; i++) Kloc[(t8 + i) * 136 + kr] = tmp[i];
    }
    const bf16* qrow = Q + (size_t)(b * 2048 + j64 + w * 16 + l16) * 512 + h * 128;
    s8v qa[4];
#pragma unroll
    for (int kc = 0; kc < 4; kc++) qa[kc] = *(const s8v*)(qrow + kc * 32 + q * 8);
    __syncthreads();
    {
        f4v sT[4];
#pragma unroll
        for (int fi = 0; fi < 4; fi++) sT[fi] = z;
#pragma unroll
        for (int kc = 0; kc < 4; kc++)
#pragma unroll
            for (int fi = 0; fi < 4; fi++) {
                s8v kb = *(s8v*)&Kloc[(fi * 16 + l16) * 136 + kc * 32 + q * 8];
                sT[fi] = mfma16(kb, qa[kc], sT[fi]);
            }
        const int tl = w * 16 + l16;
#pragma unroll
        for (int fi = 0; fi < 4; fi++) {
            alignas(8) bf16 pk[4];
#pragma unroll
            for (int r = 0; r < 4; r++) {
                int taul = fi * 16 + q * 4 + r;
                pk[r] = (taul <= tl) ? f2b(sT[fi][r]) : f2b(0.f);
            }
            *(s4v*)&Sl[tl * 72 + fi * 16 + q * 4] = *(s4v*)pk;
        }
    }
    __syncthreads();
    {
        f4v ok[4];
#pragma unroll
        for (int i = 0; i < 4; i++) ok[i] = z;
        const bf16* etrow = ET + (size_t)(bh * 64 + w * 16 + l16) * 2048 + j64;
#pragma unroll
        for (int kc = 0; kc < 2; kc++) {
            s8v ea = *(const s8v*)(etrow + kc * 32 + q * 8);
#pragma unroll
            for (int tf = 0; tf < 4; tf++) {
                s8v sb = *(s8v*)&Sl[(tf * 16 + l16) * 72 + kc * 32 + q * 8];
                ok[tf] = mfma16(ea, sb, ok[tf]);
            }
        }
        const bf16* hrow = hp + (size_t)(j64 + w * 16 + l16) * 128;
#pragma unroll
        for (int kc = 0; kc < 4; kc++) {
            s8v ha = *(const s8v*)(hrow + kc * 32 + q * 8);
#pragma unroll
            for (int tf = 0; tf < 4; tf++) {
                s8v qb = *(const s8v*)(Q + (size_t)(b * 2048 + j64 + tf * 16 + l16) * 512
                                       + h * 128 + kc * 32 + q * 8);
                ok[tf] = mfma16(ha, qb, ok[tf]);
            }
        }
#pragma unroll
        for (int tf = 0; tf < 4; tf++)
#pragma unroll
            for (int r = 0; r < 4; r++)
                okT[(w * 16 + q * 4 + r) * 65 + tf * 16 + l16] = ok[tf][r];
    }
    __syncthreads();
    for (int mi = 0; mi < 16; mi++) {
        int m = w * 16 + mi;
        float v = b2f(ET[(size_t)(bh * 64 + m) * 2048 + j64 + lane]);
#pragma unroll
        for (int off = 1; off < 64; off <<= 1) {
            float o = __shfl_up(v, off, 64);
            if (lane >= off) v += o;
        }
        float c0 = Ccp[(size_t)(b * 32 + j) * 256 + h * 64 + m];
        Ct[m * 72 + lane] = f2b(c0 + v);
    }
    __syncthreads();
    {
        const float scale = 0.08838834764831845f;
        float mx = -1e30f;
#pragma unroll
        for (int mi = 0; mi < 16; mi++) {
            int m = w * 16 + mi;
            float c = b2f(Ct[m * 72 + lane]);
            float v = okT[m * 65 + lane] * scale / c;
            okT[m * 65 + lane] = v;
            mx = fmaxf(mx, v);
        }
        swave[w * 64 + lane] = mx;
        __syncthreads();
        mx = fmaxf(fmaxf(swave[lane], swave[64 + lane]),
                   fmaxf(swave[128 + lane], swave[192 + lane]));
        float sum = 0.f;
#pragma unroll
        for (int mi = 0; mi < 16; mi++) {
            int m = w * 16 + mi;
            float e = expf(okT[m * 65 + lane] - mx);
            okT[m * 65 + lane] = e;
            sum += e;
        }
        __syncthreads();
        swave[w * 64 + lane] = sum;
        __syncthreads();
        float inv = 1.f / (swave[lane] + swave[64 + lane]
                           + swave[128 + lane] + swave[192 + lane]);
#pragma unroll
        for (int mi = 0; mi < 16; mi++) {
            int m = w * 16 + mi;
            float c = b2f(Ct[m * 72 + lane]);
            Ul[lane * 72 + m] = f2b(okT[m * 65 + lane] * inv / c);
        }
    }
    __syncthreads();
#pragma unroll
    for (int c = 0; c < 2; c++) {
        int idx = c * 256 + tid;
        int mr = idx >> 3, t8 = (idx & 7) * 8;
        alignas(16) bf16 tmp[8];
        *(s8v*)tmp = *(const s8v*)&ET[(size_t)(bh * 64 + mr) * 2048 + j64 + t8];
#pragma unroll
        for (int i = 0; i < 8; i++) Etl[(t8 + i) * 72 + mr] = tmp[i];
    }
    __syncthreads();
    {
        s8v ub[2];
#pragma unroll
        for (int kc = 0; kc < 2; kc++)
            ub[kc] = *(s8v*)&Ul[(w * 16 + l16) * 72 + kc * 32 + q * 8];
        f4v pT[4];
#pragma unroll
        for (int fi = 0; fi < 4; fi++) pT[fi] = z;
#pragma unroll
        for (int kc = 0; kc < 2; kc++)
#pragma unroll
            for (int fi = 0; fi < 4; fi++) {
                s8v eb = *(s8v*)&Etl[(fi * 16 + l16) * 72 + kc * 32 + q * 8];
                pT[fi] = mfma16(eb, ub[kc], pT[fi]);
            }
        const int tl = w * 16 + l16;
#pragma unroll
        for (int fi = 0; fi < 4; fi++) {
            alignas(8) bf16 pk[4];
#pragma unroll
            for (int r = 0; r < 4; r++) {
                int taul = fi * 16 + q * 4 + r;
                pk[r] = (taul <= tl) ? f2b(pT[fi][r]) : f2b(0.f);
            }
            *(s4v*)&Pl[tl * 72 + fi * 16 + q * 4] = *(s4v*)pk;
        }
    }
    __syncthreads();
    f4v oacc[4][4];
#pragma unroll
    for (int zc = 0; zc < 4; zc++)
#pragma unroll
        for (int i = 0; i < 4; i++) oacc[zc][i] = z;
    {
        const bf16* vtrow = VT + (size_t)(b * 1024 + h * 256 + w * 16 + l16) * 2048 + j64;
        const bf16* svrow = Svp + (size_t)((bh * 32 + j) * 256 + w * 16 + l16) * 64;
#pragma unroll
        for (int kc = 0; kc < 2; kc++) {
            s8v pb[4], ub2[4];
#pragma unroll
            for (int tf = 0; tf < 4; tf++) {
                pb[tf] = *(s8v*)&Pl[(tf * 16 + l16) * 72 + kc * 32 + q * 8];
                ub2[tf] = *(s8v*)&Ul[(tf * 16 + l16) * 72 + kc * 32 + q * 8];
            }
#pragma unroll
            for (int zc = 0; zc < 4; zc++) {
                s8v vt = *(const s8v*)(vtrow + (size_t)(zc * 64) * 2048 + kc * 32 + q * 8);
                s8v sv = *(const s8v*)(svrow + (size_t)(zc * 64) * 64 + kc * 32 + q * 8);
#pragma unroll
                for (int tf = 0; tf < 4; tf++) {
                    oacc[zc][tf] = mfma16(vt, pb[tf], oacc[zc][tf]);
                    oacc[zc][tf] = mfma16(sv, ub2[tf], oacc[zc][tf]);
                }
            }
        }
    }
    float part[4] = {0.f, 0.f, 0.f, 0.f};
#pragma unroll
    for (int zc = 0; zc < 4; zc++)
#pragma unroll
        for (int tf = 0; tf < 4; tf++)
#pragma unroll
            for (int r = 0; r < 4; r++)
                part[tf] += oacc[zc][tf][r] * oacc[zc][tf][r];
#pragma unroll
    for (int tf = 0; tf < 4; tf++) {
        part[tf] += __shfl_xor(part[tf], 16, 64);
        part[tf] += __shfl_xor(part[tf], 32, 64);
    }
    if (q == 0) {
#pragma unroll
        for (int tf = 0; tf < 4; tf++) swave[w * 64 + tf * 16 + l16] = part[tf];
    }
    const int trow = tid >> 2, vseg = (tid & 3) * 16;
    for (int zc = 0; zc < 4; zc++) {
#pragma unroll
        for (int tf = 0; tf < 4; tf++)
            *(f4v*)&Ot[(tf * 16 + l16) * 68 + w * 16 + q * 4] = oacc[zc][tf];
        __syncthreads();
        if (zc == 0) {
            if (tid < 64)
                ssum[tid] = rsqrtf((swave[tid] + swave[64 + tid] + swave[128 + tid]
                                    + swave[192 + tid]) * (1.0f / 256.0f) + 1e-5f);
            __syncthreads();
        }
        float rs = ssum[trow];
        size_t orow = (size_t)(b * 2048 + j64 + trow) * 1024 + h * 256 + zc * 64 + vseg;
        alignas(16) bf16 gh[16];
        *(s8v*)&gh[0] = *(const s8v*)&gate[orow];
        *(s8v*)&gh[8] = *(const s8v*)&gate[orow + 8];
        alignas(16) bf16 tmp[16];
#pragma unroll
        for (int i = 0; i < 16; i++) {
            float g = b2f(gh[i]);
            float sg = g / (1.f + expf(-g));
            float val = Ot[trow * 68 + vseg + i] * rs * b2f(gn[zc * 64 + vseg + i]) * sg;
            tmp[i] = f2b(val);
        }
        *(s8v*)&OV[orow] = *(s8v*)&tmp[0];
        *(s8v*)&OV[orow + 8] = *(s8v*)&tmp[8];
        __syncthreads();
    }
}

// ---------------------------------------------------------------------------
extern "C" void kernel_launch(void* const* d_in, const int* in_sizes, int n_in,
                              void* d_out, int out_size, void* d_ws, size_t ws_size,
                              hipStream_t stream)
{
    constexpr size_t MB = 1u << 20;
    char* w = (char*)d_ws;
    bf16* Xb   = (bf16*)(w + 0);                 // [0,16) -> Qb/KTb after mproj
    bf16* Qb   = (bf16*)(w + 0);                 // [0,8)
    bf16* KTb  = (bf16*)(w + 8 * MB);            // [8,16)
    bf16* WoT  = (bf16*)(w + 16 * MB);           // [16,18)
    bf16* WallT= (bf16*)(w + 18 * MB);           // [18,24.5): WqkT|WgT|WvT|WsT
    bf16* WkT  = (bf16*)(w + 19 * MB);
    bf16* WgT  = (bf16*)(w + 20 * MB);
    bf16* WvT  = (bf16*)(w + 22 * MB);
    bf16* WsT  = (bf16*)(w + 24 * MB);
    bf16* HpA  = (bf16*)(w + 18 * MB);           // [18,24) after merged GEMM
    bf16* gnwb = (bf16*)(w + 24 * MB + 524288);  // smalls [24.5,25)
    bf16* qwb  = (bf16*)(w + 24 * MB + 532480);
    bf16* kwb  = (bf16*)(w + 24 * MB + 540672);
    bf16* vwb  = (bf16*)(w + 24 * MB + 548864);
    int*  flagp= (int*) (w + 24 * MB + 565248);
    bf16* qkpre= (bf16*)(w + 25 * MB);           // [25,41) -> Svp after convs
    bf16* Svp  = (bf16*)(w + 25 * MB);
    bf16* ETb  = (bf16*)(w + 41 * MB);           // [41,45)
    bf16* vpre = (bf16*)(w + 45 * MB);           // [45,61) -> OVb after conv_v
    bf16* OVb  = (bf16*)(w + 45 * MB);
    float* Ccp = (float*)(w + 61 * MB);          // [61,61.25)
    bf16* HpB  = (bf16*)(w + 61 * MB + 262144);  // [61.25,63.25)
    bf16* VT   = (bf16*)d_out;                   // d_out[0,16MB)
    bf16* gate = (bf16*)d_out + 8 * 1024 * 1024; // d_out[16,32MB)

    dim3 blk(256);
    probe_dtype_kernel<<<1, blk, 0, stream>>>(d_in[0], flagp);
    convert_fused<<<9281, blk, 0, stream>>>(d_in[0],
                                            d_in[1], d_in[2], d_in[3], d_in[4],
                                            d_in[5], d_in[6],
                                            d_in[7], d_in[8], d_in[9], d_in[10],
                                            Xb, WallT, WkT, WvT, WsT, WgT, WoT,
                                            qwb, kwb, vwb, gnwb, flagp);
    // merged projection GEMM (256^2 tile, 4-phase): 416 = 8 XCD x 52.
    gemm256_8p<4, 8><<<416, dim3(512), 0, stream>>>(Xb, WallT, qkpre, ETb, gate,
                                                    vpre, flagp);
    // all convs in one launch (no aliasing: Qb/KTb over dead Xb).
    conv_all2_kernel<<<3072, blk, 0, stream>>>(qkpre, vpre, qwb, kwb, vwb,
                                               Qb, KTb, VT);
    tile_state_kernel<<<1280, blk, 0, stream>>>(ETb, KTb, VT, Svp, HpA, HpB, Ccp);
    prefix_state_kernel<<<1536, blk, 0, stream>>>(Svp, HpA, HpB);
    // attn writes OVb over dead vpre region.
    attn12_mfma<<<dim3(16, 32), blk, 0, stream>>>(Qb, KTb, ETb, Ccp, HpA, HpB,
                                                  Svp, VT, gate, gnwb, OVb);
    // output projection: 128x256 tiles -> 256 blocks = one full round.
    gemm256_8p<3, 4><<<256, dim3(512), 0, stream>>>(OVb, WoT, d_out, nullptr,
                                                    nullptr, nullptr, flagp);
}

// Round 10
// 352.391 us; speedup vs baseline: 1.0494x; 1.0494x over previous
//
#include <hip/hip_runtime.h>
#include <hip/hip_bf16.h>
#include <math.h>

typedef __hip_bfloat16 bf16;
typedef short s8v __attribute__((ext_vector_type(8)));
typedef short s4v __attribute__((ext_vector_type(4)));
typedef float f4v __attribute__((ext_vector_type(4)));

__device__ __forceinline__ float b2f(bf16 x) { return __bfloat162float(x); }
__device__ __forceinline__ bf16 f2b(float x) { return __float2bfloat16(x); }
__device__ __forceinline__ f4v mfma16(s8v a, s8v b, f4v c) {
    return __builtin_amdgcn_mfma_f32_16x16x32_bf16(a, b, c, 0, 0, 0);
}
__device__ __forceinline__ void async16(const bf16* g, bf16* l) {
    __builtin_amdgcn_global_load_lds(
        (const __attribute__((address_space(1))) void*)g,
        (__attribute__((address_space(3))) void*)l, 16, 0, 0);
}

constexpr int Bn = 4, Tn = 2048, Dn = 1024, KDn = 512, VDn = 1024;
constexpr int Hn = 4, Mn = 64, HKn = 128, HVn = 256;
constexpr int BT = Bn * Tn;

// ---------------------------------------------------------------------------
__global__ __launch_bounds__(256) void probe_dtype_kernel(
    const void* __restrict__ x, int* __restrict__ flag)
{
    const bf16* xb = (const bf16*)x;
    float mx = 0.f;
    for (int i = threadIdx.x; i < 4096; i += 256) {
        float v = fabsf(b2f(xb[i]));
        if (isnan(v)) v = 1e30f;
        mx = fmaxf(mx, v);
    }
    __shared__ float red[256];
    red[threadIdx.x] = mx;
    __syncthreads();
    for (int s = 128; s > 0; s >>= 1) {
        if (threadIdx.x < s) red[threadIdx.x] = fmaxf(red[threadIdx.x], red[threadIdx.x + s]);
        __syncthreads();
    }
    if (threadIdx.x == 0) flag[0] = (red[0] > 1e6f) ? 1 : 0;
}

// ---------------------------------------------------------------------------
// All input conversions in ONE launch:
//   nb < 8192          : hidden_states -> Xb (bf16), 4 elems/thread (exact)
//   nb == 8192         : small conv weights + gnorm
//   nb in (8192, 9281) : 6 weight matrices transposed (loc = nb - 8193)
// ---------------------------------------------------------------------------
__global__ __launch_bounds__(256) void convert_fused(
    const void* __restrict__ x,
    const void* s0, const void* s1, const void* s2, const void* s3,
    const void* s4, const void* s5,
    const void* sq, const void* sk, const void* sv, const void* sg,
    bf16* __restrict__ Xb,
    bf16* d0, bf16* d1, bf16* d2, bf16* d3, bf16* d4, bf16* d5,
    bf16* __restrict__ qd, bf16* __restrict__ kd,
    bf16* __restrict__ vd, bf16* __restrict__ gd,
    const int* __restrict__ flag)
{
    __shared__ bf16 tile[64 * 72];
    const int nb = blockIdx.x, tid = threadIdx.x;
    const int is32 = flag[0];
    if (nb < 8192) {
        int i0 = (nb * 256 + tid) * 4;
#pragma unroll
        for (int j = 0; j < 4; j++) {
            int i = i0 + j;
            if (i < BT * Dn)
                Xb[i] = is32 ? f2b(((const float*)x)[i]) : ((const bf16*)x)[i];
        }
    } else if (nb == 8192) {
        for (int i = tid; i < 8448; i += 256) {
            const void* s; bf16* d; int l;
            if (i < 2048)      { s = sq; d = qd; l = i; }
            else if (i < 4096) { s = sk; d = kd; l = i - 2048; }
            else if (i < 8192) { s = sv; d = vd; l = i - 4096; }
            else               { s = sg; d = gd; l = i - 8192; }
            d[l] = is32 ? f2b(((const float*)s)[l]) : ((const bf16*)s)[l];
        }
    } else {
        int nb2 = nb - 8193;
        const void* src; bf16* dst; int K, N, loc;
        if (nb2 < 128)       { src = s0; dst = d0; K = 1024; N = 512;  loc = nb2; }
        else if (nb2 < 256)  { src = s1; dst = d1; K = 1024; N = 512;  loc = nb2 - 128; }
        else if (nb2 < 512)  { src = s2; dst = d2; K = 1024; N = 1024; loc = nb2 - 256; }
        else if (nb2 < 576)  { src = s3; dst = d3; K = 1024; N = 256;  loc = nb2 - 512; }
        else if (nb2 < 832)  { src = s4; dst = d4; K = 1024; N = 1024; loc = nb2 - 576; }
        else                 { src = s5; dst = d5; K = 1024; N = 1024; loc = nb2 - 832; }
        int nt = N >> 6;
        int n0 = (loc % nt) * 64, k0 = (loc / nt) * 64;
        int r = tid >> 2, seg = (tid & 3) * 16;
#pragma unroll
        for (int i = 0; i < 16; i++) {
            size_t gi = (size_t)(k0 + r) * N + n0 + seg + i;
            float v = is32 ? ((const float*)src)[gi] : b2f(((const bf16*)src)[gi]);
            tile[r * 72 + seg + i] = f2b(v);
        }
        __syncthreads();
        bf16 tmp[16];
#pragma unroll
        for (int i = 0; i < 16; i++) tmp[i] = tile[(seg + i) * 72 + r];
        size_t o = (size_t)(n0 + r) * K + k0 + seg;
        *(s8v*)&dst[o] = *(s8v*)&tmp[0];
        *(s8v*)&dst[o + 8] = *(s8v*)&tmp[8];
    }
}

// ---------------------------------------------------------------------------
// BM x 256 tile GEMM (BM = MF*32), m201-style 4-phase schedule.
// MF=8 (EP4): identical structure to the r6/r7-verified kernel.
// MF=4 (EP3): 128x256 tiles -> grid 256 blocks = one full round.
// Ledger (both MF): per tile issues = A(MF/2) + B(4); at phase3,
// outstanding = A(t+1)(MF/2) + B(t+2)(4) -> vmcnt(4) forces A(t+1)
// and all older (incl B(t+1)), leaves B(t+2) in flight.
// Prologue: B(0)4, A(0)MF/2, B(1)4 -> vmcnt(4) leaves exactly B(1).
// Direct-store epilogue (r9 showed LDS-staged vectorization regresses:
// scattered 2B stores are absorbed by L2 write-combining at ~zero cost).
// ---------------------------------------------------------------------------
template <int EP, int MF>
__global__ __launch_bounds__(512, 2) void gemm256_8p(
    const bf16* __restrict__ A, const bf16* __restrict__ Bt,
    void* __restrict__ Cout, bf16* __restrict__ ETout,
    bf16* __restrict__ aux1, bf16* __restrict__ aux2,
    const int* __restrict__ flag)
{
    constexpr int BM = MF * 32;          // 256 or 128
    constexpr int ASZ = BM * 64;         // A buffer elems (16384 / 8192)
    constexpr int PM = MF / 4;           // m-frags per phase (2 / 1)
    __shared__ bf16 lds[2 * ASZ + 2 * 16384];
    constexpr int K = 1024, NT = 16;
    const int tid = threadIdx.x;
    const int w8 = tid >> 6, lane = tid & 63;
    const int l16 = lane & 15, q2 = lane >> 4;
    const int wr = w8 >> 2, wc = w8 & 3;

    const int bid = blockIdx.x;
    const int xcd = bid & 7, ii = bid >> 3;
    int bx, by;
    if (EP == 4) {
        if (ii < 48) {
            int sc = ii >> 3, rem = ii & 7;
            bx = sc * 2 + (rem & 1);
            by = xcd * 4 + (rem >> 1);
        } else {
            bx = 12;
            by = xcd * 4 + (ii - 48);
        }
    } else {
        bx = ii >> 3;            // 0..3
        by = xcd * 8 + (ii & 7); // 0..63
    }

    const int srow = tid >> 3;
    const int sslot = (tid & 7) ^ (srow & 7);
    const bf16* gA0 = A + (size_t)(by * BM + srow) * K + sslot * 8;
    const bf16* gB0 = Bt + (size_t)(bx * 256 + srow) * K + sslot * 8;
    const int dOff = w8 * 512;

    const int sz0 = ((q2 ^ (l16 & 7))) * 8;
    const int sz1 = (((q2 ^ 4) ^ (l16 & 7))) * 8;
    const int rowA = (wr * (MF * 16) + l16) * 64;

    f4v acc[MF][4];
    f4v z = {0.f, 0.f, 0.f, 0.f};
#pragma unroll
    for (int i = 0; i < MF; i++)
#pragma unroll
        for (int j = 0; j < 4; j++) acc[i][j] = z;

    // prologue: B(0) 4, A(0) MF/2, B(1) 4
#pragma unroll
    for (int g = 0; g < 4; ++g)
        async16(gB0 + (size_t)g * 64 * K, &lds[2 * ASZ] + g * 4096 + dOff);
#pragma unroll
    for (int g = 0; g < MF / 2; ++g)
        async16(gA0 + (size_t)g * 64 * K, &lds[0] + g * 4096 + dOff);
#pragma unroll
    for (int g = 0; g < 4; ++g)
        async16(gB0 + (size_t)g * 64 * K + 64, &lds[2 * ASZ + 16384] + g * 4096 + dOff);
    asm volatile("s_waitcnt vmcnt(4)" ::: "memory");
    __builtin_amdgcn_s_barrier();

    for (int t = 0; t < NT; ++t) {
        const int da = t & 1;
        const bf16* bufA = &lds[da * ASZ];
        const bf16* bufB = &lds[2 * ASZ + da * 16384];
        bf16* stA = &lds[(da ^ 1) * ASZ];
        bf16* stB = &lds[2 * ASZ + da * 16384];
        const int tA = (t + 1 < NT) ? (t + 1) : (NT - 1);
        const int tB = (t + 2 < NT) ? (t + 2) : (NT - 1);
        s8v breg[4][2];
#pragma unroll
        for (int q = 0; q < 4; ++q) {
            if (q == 0) {
#pragma unroll
                for (int ni = 0; ni < 4; ++ni) {
                    int rb = (wc * 64 + ni * 16 + l16) * 64;
                    breg[ni][0] = *(const s8v*)(bufB + rb + sz0);
                    breg[ni][1] = *(const s8v*)(bufB + rb + sz1);
                }
            }
            s8v aq[PM][2];
#pragma unroll
            for (int m = 0; m < PM; ++m) {
                int ra = rowA + (q * PM + m) * 1024;
                aq[m][0] = *(const s8v*)(bufA + ra + sz0);
                aq[m][1] = *(const s8v*)(bufA + ra + sz1);
            }
            if (q == 0) {
#pragma unroll
                for (int g = 0; g < MF / 2; ++g)
                    async16(gA0 + (size_t)tA * 64 + (size_t)g * 64 * K,
                            stA + g * 4096 + dOff);
            } else if (q == 1) {
#pragma unroll
                for (int g = 0; g < 2; ++g)
                    async16(gB0 + (size_t)tB * 64 + (size_t)g * 64 * K,
                            stB + g * 4096 + dOff);
            } else if (q == 2) {
#pragma unroll
                for (int g = 2; g < 4; ++g)
                    async16(gB0 + (size_t)tB * 64 + (size_t)g * 64 * K,
                            stB + g * 4096 + dOff);
            } else {
                asm volatile("s_waitcnt vmcnt(4)" ::: "memory");
            }
            __builtin_amdgcn_s_barrier();
            asm volatile("s_waitcnt lgkmcnt(0)" ::: "memory");
            __builtin_amdgcn_sched_barrier(0);
            __builtin_amdgcn_s_setprio(1);
#pragma unroll
            for (int kq = 0; kq < 2; ++kq)
#pragma unroll
                for (int m = 0; m < PM; ++m)
#pragma unroll
                    for (int ni = 0; ni < 4; ++ni)
                        acc[q * PM + m][ni] =
                            mfma16(aq[m][kq], breg[ni][kq], acc[q * PM + m][ni]);
            __builtin_amdgcn_s_setprio(0);
            __builtin_amdgcn_s_barrier();
        }
    }
    asm volatile("s_waitcnt vmcnt(0)" ::: "memory");

    const int row0 = by * BM + wr * (MF * 16) + q2 * 4;
    const int col0 = bx * 256 + wc * 64 + l16;
    if (EP == 4) {
        if (bx < 12) {
            bf16* dst = (bx < 4) ? (bf16*)Cout : (bx < 8 ? aux1 : aux2);
            const int cb = (bx < 4) ? 0 : (bx < 8 ? 1024 : 2048);
#pragma unroll
            for (int mi = 0; mi < MF; ++mi)
#pragma unroll
                for (int ni = 0; ni < 4; ++ni)
#pragma unroll
                    for (int r = 0; r < 4; ++r) {
                        int row = row0 + mi * 16 + r;
                        int col = col0 + ni * 16 - cb;
                        dst[(size_t)row * 1024 + col] = f2b(acc[mi][ni][r]);
                    }
        } else {
#pragma unroll
            for (int mi = 0; mi < MF; ++mi)
#pragma unroll
                for (int ni = 0; ni < 4; ++ni)
#pragma unroll
                    for (int r = 0; r < 4; ++r) {
                        int row = row0 + mi * 16 + r;
                        int c = wc * 64 + ni * 16 + l16;
                        float v = acc[mi][ni][r];
                        float cl = fminf(32.f, fmaxf(-32.f, v));
                        int b_ = row >> 11, t_ = row & 2047;
                        int h_ = c >> 6, m_ = c & 63;
                        ETout[((size_t)((b_ * 4 + h_) * 64 + m_)) * 2048 + t_]
                            = f2b(expf(cl));
                    }
        }
    } else {
        const int dyn = flag[0];
#pragma unroll
        for (int mi = 0; mi < MF; ++mi)
#pragma unroll
            for (int ni = 0; ni < 4; ++ni)
#pragma unroll
                for (int r = 0; r < 4; ++r) {
                    int row = row0 + mi * 16 + r;
                    int col = col0 + ni * 16;
                    float v = acc[mi][ni][r];
                    size_t idx = (size_t)row * 1024 + col;
                    if (dyn) ((float*)Cout)[idx] = v;
                    else ((bf16*)Cout)[idx] = f2b(v);
                }
    }
}

// ---------------------------------------------------------------------------
// conv + silu for v -> VT[b*1024 + c][t]  (2048 blocks). Runs before
// conv_qk (Qb/KTb alias vpre).
// ---------------------------------------------------------------------------
__global__ __launch_bounds__(256) void conv_v_kernel(
    const bf16* __restrict__ pre, const bf16* __restrict__ w,
    bf16* __restrict__ VT)
{
    __shared__ bf16 tile[64 * 72];
    int nb = blockIdx.x;
    int c0 = (nb & 15) * 64, t0 = ((nb >> 4) & 31) * 64, b = nb >> 9;
    int tid = threadIdx.x;
    int row = tid >> 2, seg = (tid & 3) * 16;
    float y[16];
#pragma unroll
    for (int i = 0; i < 16; i++) y[i] = 0.f;
#pragma unroll
    for (int j = 0; j < 4; j++) {
        int tt = t0 + row - 3 + j;
        if (tt >= 0) {
            const bf16* p = &pre[(size_t)(b * Tn + tt) * VDn + c0 + seg];
#pragma unroll
            for (int i = 0; i < 16; i++)
                y[i] += b2f(p[i]) * b2f(w[(c0 + seg + i) * 4 + j]);
        }
    }
#pragma unroll
    for (int i = 0; i < 16; i++) {
        float v = y[i] / (1.f + expf(-y[i]));
        tile[row * 72 + seg + i] = f2b(v);
    }
    __syncthreads();
    bf16 tmp[16];
#pragma unroll
    for (int i = 0; i < 16; i++) tmp[i] = tile[(seg + i) * 72 + row];
    size_t o = (size_t)(b * 1024 + c0 + row) * 2048 + t0 + seg;
    *(s8v*)&VT[o] = *(s8v*)&tmp[0];
    *(s8v*)&VT[o + 8] = *(s8v*)&tmp[8];
}

// ---------------------------------------------------------------------------
// conv_qk: nb<512 -> q (vectorized conv+silu+rope); [512,1024) -> k
// (conv+silu+rope, transposed out; full 512-block coverage).
// ---------------------------------------------------------------------------
__global__ __launch_bounds__(256) void conv_qk_kernel(
    const bf16* __restrict__ qkpre, const bf16* __restrict__ qw,
    const bf16* __restrict__ kw,
    bf16* __restrict__ Qb, bf16* __restrict__ KT)
{
    __shared__ bf16 tile[128 * 72];
    const int nb = blockIdx.x, tid = threadIdx.x;
    if (nb < 512) {
        const int h = nb & 3, tt = (nb >> 2) & 31, b = nb >> 7;
        const int row = tid >> 2, seg = (tid & 3) * 16;
        const int t = tt * 64 + row;
        const int clo = h * 128 + seg;
        float ylo[16], yhi[16];
#pragma unroll
        for (int i = 0; i < 16; i++) { ylo[i] = 0.f; yhi[i] = 0.f; }
        alignas(16) bf16 wlo[64], whi[64];
#pragma unroll
        for (int c = 0; c < 8; c++) {
            *(s8v*)&wlo[c * 8] = *(const s8v*)&qw[clo * 4 + c * 8];
            *(s8v*)&whi[c * 8] = *(const s8v*)&qw[(clo + 64) * 4 + c * 8];
        }
#pragma unroll
        for (int j = 0; j < 4; j++) {
            int ts = t - 3 + j;
            if (ts >= 0) {
                const bf16* p = &qkpre[(size_t)(b * Tn + ts) * 1024 + clo];
                alignas(16) bf16 xl[16], xh[16];
                *(s8v*)&xl[0] = *(const s8v*)p;
                *(s8v*)&xl[8] = *(const s8v*)(p + 8);
                *(s8v*)&xh[0] = *(const s8v*)(p + 64);
                *(s8v*)&xh[8] = *(const s8v*)(p + 72);
#pragma unroll
                for (int i = 0; i < 16; i++) {
                    ylo[i] += b2f(xl[i]) * b2f(wlo[i * 4 + j]);
                    yhi[i] += b2f(xh[i]) * b2f(whi[i * 4 + j]);
                }
            }
        }
        alignas(16) bf16 olo[16], ohi[16];
#pragma unroll
        for (int i = 0; i < 16; i++) {
            float yl = ylo[i] / (1.f + expf(-ylo[i]));
            float yh = yhi[i] / (1.f + expf(-yhi[i]));
            float invf = exp2f(-(float)(seg + i) * 0.2076205059304601f);
            float th = (float)t * invf;
            float c = cosf(th), s = sinf(th);
            olo[i] = f2b(yl * c - yh * s);
            ohi[i] = f2b(yh * c + yl * s);
        }
        size_t rb = (size_t)(b * Tn + t) * KDn + clo;
        *(s8v*)&Qb[rb] = *(s8v*)&olo[0];
        *(s8v*)&Qb[rb + 8] = *(s8v*)&olo[8];
        *(s8v*)&Qb[rb + 64] = *(s8v*)&ohi[0];
        *(s8v*)&Qb[rb + 72] = *(s8v*)&ohi[8];
    } else {
        int r = nb - 512;
        const int tt = r & 31, h = (r >> 5) & 3, b = r >> 7;
        const int dp = tid >> 2, tq = tid & 3;
        const int clo = 512 + h * 128 + dp, chi = clo + 64;
        const float w0l = b2f(kw[(h * 128 + dp) * 4 + 0]), w1l = b2f(kw[(h * 128 + dp) * 4 + 1]),
                    w2l = b2f(kw[(h * 128 + dp) * 4 + 2]), w3l = b2f(kw[(h * 128 + dp) * 4 + 3]);
        const float w0h = b2f(kw[(h * 128 + dp + 64) * 4 + 0]), w1h = b2f(kw[(h * 128 + dp + 64) * 4 + 1]),
                    w2h = b2f(kw[(h * 128 + dp + 64) * 4 + 2]), w3h = b2f(kw[(h * 128 + dp + 64) * 4 + 3]);
        const float invf = exp2f(-(float)dp * 0.2076205059304601f);
        float l0 = 0.f, l1 = 0.f, l2 = 0.f, h0 = 0.f, h1 = 0.f, h2 = 0.f;
        int tg0 = tt * 64 + tq * 16;
#pragma unroll
        for (int p = 0; p < 3; p++) {
            int tg = tg0 - 3 + p;
            float xl = 0.f, xh = 0.f;
            if (tg >= 0) {
                size_t rb = (size_t)(b * Tn + tg) * 1024;
                xl = b2f(qkpre[rb + clo]);
                xh = b2f(qkpre[rb + chi]);
            }
            l0 = l1; l1 = l2; l2 = xl;
            h0 = h1; h1 = h2; h2 = xh;
        }
        for (int i = 0; i < 16; i++) {
            int tg = tg0 + i;
            size_t rb = (size_t)(b * Tn + tg) * 1024;
            float xl = b2f(qkpre[rb + clo]);
            float xh = b2f(qkpre[rb + chi]);
            float ylo = l0 * w0l + l1 * w1l + l2 * w2l + xl * w3l;
            float yhi = h0 * w0h + h1 * w1h + h2 * w2h + xh * w3h;
            l0 = l1; l1 = l2; l2 = xl;
            h0 = h1; h1 = h2; h2 = xh;
            ylo = ylo / (1.f + expf(-ylo));
            yhi = yhi / (1.f + expf(-yhi));
            float th = (float)tg * invf;
            float c = cosf(th), s = sinf(th);
            int tl = tq * 16 + i;
            tile[dp * 72 + tl] = f2b(ylo * c - yhi * s);
            tile[(dp + 64) * 72 + tl] = f2b(yhi * c + ylo * s);
        }
        __syncthreads();
#pragma unroll
        for (int c = 0; c < 4; c++) {
            int idx = c * 256 + tid;
            int ch = idx >> 3, t8 = (idx & 7) * 8;
            s8v v = *(s8v*)&tile[ch * 72 + t8];
            *(s8v*)&KT[((size_t)((b * 4 + h) * 128 + ch)) * 2048 + tt * 64 + t8] = v;
        }
    }
}

// ---------------------------------------------------------------------------
// Phase A + cumsum merged (unchanged).
// ---------------------------------------------------------------------------
__global__ __launch_bounds__(256) void tile_state_kernel(
    const bf16* __restrict__ ET, const bf16* __restrict__ KT,
    const bf16* __restrict__ VT,
    bf16* __restrict__ Svp, bf16* __restrict__ HpA, bf16* __restrict__ HpB,
    float* __restrict__ Ccp)
{
    const int tid = threadIdx.x;
    const int w = tid >> 6, lane = tid & 63;
    const int l16 = lane & 15, q = lane >> 4;
    f4v z = {0.f, 0.f, 0.f, 0.f};
    if (blockIdx.x < 512) {
        const int bh = blockIdx.x >> 5, j = blockIdx.x & 31;
        const int b = bh >> 2, h = bh & 3;
        const int j64 = j * 64;
        f4v acc[4][4];
#pragma unroll
        for (int i = 0; i < 4; i++)
#pragma unroll
            for (int jj = 0; jj < 4; jj++) acc[i][jj] = z;
#pragma unroll
        for (int kc = 0; kc < 2; kc++) {
            s8v va[4], eb[4];
#pragma unroll
            for (int vf = 0; vf < 4; vf++)
                va[vf] = *(const s8v*)(VT + (size_t)(b * 1024 + h * 256 + w * 64 + vf * 16 + l16) * 2048
                                       + j64 + kc * 32 + q * 8);
#pragma unroll
            for (int mf = 0; mf < 4; mf++)
                eb[mf] = *(const s8v*)(ET + (size_t)(bh * 64 + mf * 16 + l16) * 2048
                                       + j64 + kc * 32 + q * 8);
#pragma unroll
            for (int vf = 0; vf < 4; vf++)
#pragma unroll
                for (int mf = 0; mf < 4; mf++)
                    acc[vf][mf] = mfma16(va[vf], eb[mf], acc[vf][mf]);
        }
#pragma unroll
        for (int vf = 0; vf < 4; vf++)
#pragma unroll
            for (int mf = 0; mf < 4; mf++)
#pragma unroll
                for (int r = 0; r < 4; r++)
                    Svp[((size_t)((bh * 32 + j) * 256 + w * 64 + vf * 16 + q * 4 + r)) * 64
                        + mf * 16 + l16] = f2b(acc[vf][mf][r]);
    } else if (blockIdx.x < 1024) {
        const int idx = blockIdx.x - 512;
        const int bh = idx >> 5, j = idx & 31;
        const int j64 = j * 64;
        bf16* hp = (bh < 12) ? (HpA + (size_t)bh * 262144)
                             : (HpB + (size_t)(bh - 12) * 262144);
        f4v acc[8];
#pragma unroll
        for (int i = 0; i < 8; i++) acc[i] = z;
#pragma unroll
        for (int kc = 0; kc < 2; kc++) {
            s8v ea = *(const s8v*)(ET + (size_t)(bh * 64 + w * 16 + l16) * 2048
                                   + j64 + kc * 32 + q * 8);
#pragma unroll
            for (int kf = 0; kf < 8; kf++) {
                s8v kb = *(const s8v*)(KT + (size_t)(bh * 128 + kf * 16 + l16) * 2048
                                       + j64 + kc * 32 + q * 8);
                acc[kf] = mfma16(ea, kb, acc[kf]);
            }
        }
#pragma unroll
        for (int kf = 0; kf < 8; kf++)
#pragma unroll
            for (int r = 0; r < 4; r++)
                hp[((size_t)(j64 + w * 16 + q * 4 + r)) * 128 + kf * 16 + l16]
                    = f2b(acc[kf][r]);
    } else {
        int row = (blockIdx.x - 1024) * 4 + w;
        int b = row >> 8, hm = row & 255;
        const bf16* src = ET + (size_t)row * 2048;
        float run = 0.f;
        for (int ch = 0; ch < 32; ch++) {
            if (lane == 0) Ccp[(size_t)(b * 32 + ch) * 256 + hm] = run;
            float v = b2f(src[ch * 64 + lane]);
#pragma unroll
            for (int off = 1; off < 64; off <<= 1) {
                float o = __shfl_up(v, off, 64);
                if (lane >= off) v += o;
            }
            run += __shfl(v, 63, 64);
        }
    }
}

// ---------------------------------------------------------------------------
// Phase B: in-place exclusive prefix over j (unchanged).
// ---------------------------------------------------------------------------
__global__ __launch_bounds__(256) void prefix_state_kernel(
    bf16* __restrict__ Svp, bf16* __restrict__ HpA, bf16* __restrict__ HpB)
{
    if (blockIdx.x < 1024) {
        int gid = blockIdx.x * 256 + threadIdx.x;
        int bh = gid >> 14, e = gid & 16383;
        bf16* p = Svp + (size_t)bh * 524288 + e;
        float run = 0.f;
#pragma unroll 4
        for (int j = 0; j < 32; j++) {
            float x = b2f(p[(size_t)j * 16384]);
            p[(size_t)j * 16384] = f2b(run);
            run += x;
        }
    } else {
        int gid = (blockIdx.x - 1024) * 256 + threadIdx.x;
        int bh = gid >> 13, e = gid & 8191;
        bf16* hp = ((bh < 12) ? (HpA + (size_t)bh * 262144)
                              : (HpB + (size_t)(bh - 12) * 262144)) + e;
        float run = 0.f;
#pragma unroll 4
        for (int j = 0; j < 32; j++) {
            float x = b2f(hp[(size_t)j * 8192]);
            hp[(size_t)j * 8192] = f2b(run);
            run += x;
        }
    }
}

// ---------------------------------------------------------------------------
// Fused attention (parallel softmax; unchanged from r8).
// ---------------------------------------------------------------------------
__global__ __launch_bounds__(256) void attn12_mfma(
    const bf16* __restrict__ Q, const bf16* __restrict__ KT,
    const bf16* __restrict__ ET, const float* __restrict__ Ccp,
    const bf16* __restrict__ HpA, const bf16* __restrict__ HpB,
    const bf16* __restrict__ Svp, const bf16* __restrict__ VT,
    const bf16* __restrict__ gate, const bf16* __restrict__ gn,
    bf16* __restrict__ OV)
{
    __shared__ char smem[53760];
    bf16*  Kloc = (bf16*)smem;
    float* Ot   = (float*)smem;
    bf16*  Sl   = (bf16*)(smem + 17408);
    bf16*  Ct   = (bf16*)(smem + 17408);
    bf16*  Etl  = (bf16*)(smem + 17408);
    float* okT  = (float*)(smem + 26624);
    bf16*  Pl   = (bf16*)(smem + 26624);
    bf16*  Ul   = (bf16*)(smem + 43264);
    float* swave= (float*)(smem + 52480);
    float* ssum = (float*)(smem + 53504);
    const int tid = threadIdx.x;
    const int w = tid >> 6, lane = tid & 63;
    const int l16 = lane & 15, q = lane >> 4;
    const int bh = blockIdx.x, b = bh >> 2, h = bh & 3;
    const int j = blockIdx.y, j64 = j * 64;
    f4v z = {0.f, 0.f, 0.f, 0.f};
    const bf16* hp = (bh < 12) ? (HpA + (size_t)bh * 262144)
                               : (HpB + (size_t)(bh - 12) * 262144);

#pragma unroll
    for (int c = 0; c < 4; c++) {
        int idx = c * 256 + tid;
        int kr = idx >> 3, t8 = (idx & 7) * 8;
        alignas(16) bf16 tmp[8];
        *(s8v*)tmp = *(const s8v*)&KT[((size_t)(bh * 128 + kr)) * 2048 + j64 + t8];
#pragma unroll
        for (int i = 0; i < 8; i++) Kloc[(t8 + i) * 136 + kr] = tmp[i];
    }
    const bf16* qrow = Q + (size_t)(b * 2048 + j64 + w * 16 + l16) * 512 + h * 128;
    s8v qa[4];
#pragma unroll
    for (int kc = 0; kc < 4; kc++) qa[kc] = *(const s8v*)(qrow + kc * 32 + q * 8);
    __syncthreads();
    {
        f4v sT[4];
#pragma unroll
        for (int fi = 0; fi < 4; fi++) sT[fi] = z;
#pragma unroll
        for (int kc = 0; kc < 4; kc++)
#pragma unroll
            for (int fi = 0; fi < 4; fi++) {
                s8v kb = *(s8v*)&Kloc[(fi * 16 + l16) * 136 + kc * 32 + q * 8];
                sT[fi] = mfma16(kb, qa[kc], sT[fi]);
            }
        const int tl = w * 16 + l16;
#pragma unroll
        for (int fi = 0; fi < 4; fi++) {
            alignas(8) bf16 pk[4];
#pragma unroll
            for (int r = 0; r < 4; r++) {
                int taul = fi * 16 + q * 4 + r;
                pk[r] = (taul <= tl) ? f2b(sT[fi][r]) : f2b(0.f);
            }
            *(s4v*)&Sl[tl * 72 + fi * 16 + q * 4] = *(s4v*)pk;
        }
    }
    __syncthreads();
    {
        f4v ok[4];
#pragma unroll
        for (int i = 0; i < 4; i++) ok[i] = z;
        const bf16* etrow = ET + (size_t)(bh * 64 + w * 16 + l16) * 2048 + j64;
#pragma unroll
        for (int kc = 0; kc < 2; kc++) {
            s8v ea = *(const s8v*)(etrow + kc * 32 + q * 8);
#pragma unroll
            for (int tf = 0; tf < 4; tf++) {
                s8v sb = *(s8v*)&Sl[(tf * 16 + l16) * 72 + kc * 32 + q * 8];
                ok[tf] = mfma16(ea, sb, ok[tf]);
            }
        }
        const bf16* hrow = hp + (size_t)(j64 + w * 16 + l16) * 128;
#pragma unroll
        for (int kc = 0; kc < 4; kc++) {
            s8v ha = *(const s8v*)(hrow + kc * 32 + q * 8);
#pragma unroll
            for (int tf = 0; tf < 4; tf++) {
                s8v qb = *(const s8v*)(Q + (size_t)(b * 2048 + j64 + tf * 16 + l16) * 512
                                       + h * 128 + kc * 32 + q * 8);
                ok[tf] = mfma16(ha, qb, ok[tf]);
            }
        }
#pragma unroll
        for (int tf = 0; tf < 4; tf++)
#pragma unroll
            for (int r = 0; r < 4; r++)
                okT[(w * 16 + q * 4 + r) * 65 + tf * 16 + l16] = ok[tf][r];
    }
    __syncthreads();
    for (int mi = 0; mi < 16; mi++) {
        int m = w * 16 + mi;
        float v = b2f(ET[(size_t)(bh * 64 + m) * 2048 + j64 + lane]);
#pragma unroll
        for (int off = 1; off < 64; off <<= 1) {
            float o = __shfl_up(v, off, 64);
            if (lane >= off) v += o;
        }
        float c0 = Ccp[(size_t)(b * 32 + j) * 256 + h * 64 + m];
        Ct[m * 72 + lane] = f2b(c0 + v);
    }
    __syncthreads();
    {
        const float scale = 0.08838834764831845f;
        float mx = -1e30f;
#pragma unroll
        for (int mi = 0; mi < 16; mi++) {
            int m = w * 16 + mi;
            float c = b2f(Ct[m * 72 + lane]);
            float v = okT[m * 65 + lane] * scale / c;
            okT[m * 65 + lane] = v;
            mx = fmaxf(mx, v);
        }
        swave[w * 64 + lane] = mx;
        __syncthreads();
        mx = fmaxf(fmaxf(swave[lane], swave[64 + lane]),
                   fmaxf(swave[128 + lane], swave[192 + lane]));
        float sum = 0.f;
#pragma unroll
        for (int mi = 0; mi < 16; mi++) {
            int m = w * 16 + mi;
            float e = expf(okT[m * 65 + lane] - mx);
            okT[m * 65 + lane] = e;
            sum += e;
        }
        __syncthreads();
        swave[w * 64 + lane] = sum;
        __syncthreads();
        float inv = 1.f / (swave[lane] + swave[64 + lane]
                           + swave[128 + lane] + swave[192 + lane]);
#pragma unroll
        for (int mi = 0; mi < 16; mi++) {
            int m = w * 16 + mi;
            float c = b2f(Ct[m * 72 + lane]);
            Ul[lane * 72 + m] = f2b(okT[m * 65 + lane] * inv / c);
        }
    }
    __syncthreads();
#pragma unroll
    for (int c = 0; c < 2; c++) {
        int idx = c * 256 + tid;
        int mr = idx >> 3, t8 = (idx & 7) * 8;
        alignas(16) bf16 tmp[8];
        *(s8v*)tmp = *(const s8v*)&ET[(size_t)(bh * 64 + mr) * 2048 + j64 + t8];
#pragma unroll
        for (int i = 0; i < 8; i++) Etl[(t8 + i) * 72 + mr] = tmp[i];
    }
    __syncthreads();
    {
        s8v ub[2];
#pragma unroll
        for (int kc = 0; kc < 2; kc++)
            ub[kc] = *(s8v*)&Ul[(w * 16 + l16) * 72 + kc * 32 + q * 8];
        f4v pT[4];
#pragma unroll
        for (int fi = 0; fi < 4; fi++) pT[fi] = z;
#pragma unroll
        for (int kc = 0; kc < 2; kc++)
#pragma unroll
            for (int fi = 0; fi < 4; fi++) {
                s8v eb = *(s8v*)&Etl[(fi * 16 + l16) * 72 + kc * 32 + q * 8];
                pT[fi] = mfma16(eb, ub[kc], pT[fi]);
            }
        const int tl = w * 16 + l16;
#pragma unroll
        for (int fi = 0; fi < 4; fi++) {
            alignas(8) bf16 pk[4];
#pragma unroll
            for (int r = 0; r < 4; r++) {
                int taul = fi * 16 + q * 4 + r;
                pk[r] = (taul <= tl) ? f2b(pT[fi][r]) : f2b(0.f);
            }
            *(s4v*)&Pl[tl * 72 + fi * 16 + q * 4] = *(s4v*)pk;
        }
    }
    __syncthreads();
    f4v oacc[4][4];
#pragma unroll
    for (int zc = 0; zc < 4; zc++)
#pragma unroll
        for (int i = 0; i < 4; i++) oacc[zc][i] = z;
    {
        const bf16* vtrow = VT + (size_t)(b * 1024 + h * 256 + w * 16 + l16) * 2048 + j64;
        const bf16* svrow = Svp + (size_t)((bh * 32 + j) * 256 + w * 16 + l16) * 64;
#pragma unroll
        for (int kc = 0; kc < 2; kc++) {
            s8v pb[4], ub2[4];
#pragma unroll
            for (int tf = 0; tf < 4; tf++) {
                pb[tf] = *(s8v*)&Pl[(tf * 16 + l16) * 72 + kc * 32 + q * 8];
                ub2[tf] = *(s8v*)&Ul[(tf * 16 + l16) * 72 + kc * 32 + q * 8];
            }
#pragma unroll
            for (int zc = 0; zc < 4; zc++) {
                s8v vt = *(const s8v*)(vtrow + (size_t)(zc * 64) * 2048 + kc * 32 + q * 8);
                s8v sv = *(const s8v*)(svrow + (size_t)(zc * 64) * 64 + kc * 32 + q * 8);
#pragma unroll
                for (int tf = 0; tf < 4; tf++) {
                    oacc[zc][tf] = mfma16(vt, pb[tf], oacc[zc][tf]);
                    oacc[zc][tf] = mfma16(sv, ub2[tf], oacc[zc][tf]);
                }
            }
        }
    }
    float part[4] = {0.f, 0.f, 0.f, 0.f};
#pragma unroll
    for (int zc = 0; zc < 4; zc++)
#pragma unroll
        for (int tf = 0; tf < 4; tf++)
#pragma unroll
            for (int r = 0; r < 4; r++)
                part[tf] += oacc[zc][tf][r] * oacc[zc][tf][r];
#pragma unroll
    for (int tf = 0; tf < 4; tf++) {
        part[tf] += __shfl_xor(part[tf], 16, 64);
        part[tf] += __shfl_xor(part[tf], 32, 64);
    }
    if (q == 0) {
#pragma unroll
        for (int tf = 0; tf < 4; tf++) swave[w * 64 + tf * 16 + l16] = part[tf];
    }
    const int trow = tid >> 2, vseg = (tid & 3) * 16;
    for (int zc = 0; zc < 4; zc++) {
#pragma unroll
        for (int tf = 0; tf < 4; tf++)
            *(f4v*)&Ot[(tf * 16 + l16) * 68 + w * 16 + q * 4] = oacc[zc][tf];
        __syncthreads();
        if (zc == 0) {
            if (tid < 64)
                ssum[tid] = rsqrtf((swave[tid] + swave[64 + tid] + swave[128 + tid]
                                    + swave[192 + tid]) * (1.0f / 256.0f) + 1e-5f);
            __syncthreads();
        }
        float rs = ssum[trow];
        size_t orow = (size_t)(b * 2048 + j64 + trow) * 1024 + h * 256 + zc * 64 + vseg;
        alignas(16) bf16 gh[16];
        *(s8v*)&gh[0] = *(const s8v*)&gate[orow];
        *(s8v*)&gh[8] = *(const s8v*)&gate[orow + 8];
        alignas(16) bf16 tmp[16];
#pragma unroll
        for (int i = 0; i < 16; i++) {
            float g = b2f(gh[i]);
            float sg = g / (1.f + expf(-g));
            float val = Ot[trow * 68 + vseg + i] * rs * b2f(gn[zc * 64 + vseg + i]) * sg;
            tmp[i] = f2b(val);
        }
        *(s8v*)&OV[orow] = *(s8v*)&tmp[0];
        *(s8v*)&OV[orow + 8] = *(s8v*)&tmp[8];
        __syncthreads();
    }
}

// ---------------------------------------------------------------------------
extern "C" void kernel_launch(void* const* d_in, const int* in_sizes, int n_in,
                              void* d_out, int out_size, void* d_ws, size_t ws_size,
                              hipStream_t stream)
{
    constexpr size_t MB = 1u << 20;
    char* w = (char*)d_ws;
    bf16* Xb   = (bf16*)(w + 0);                 // [0,16) -> OV after merged GEMM
    bf16* OVb  = (bf16*)(w + 0);
    bf16* WoT  = (bf16*)(w + 16 * MB);           // [16,18)
    bf16* WallT= (bf16*)(w + 18 * MB);           // [18,24.5): WqkT|WgT|WvT|WsT
    bf16* WkT  = (bf16*)(w + 19 * MB);
    bf16* WgT  = (bf16*)(w + 20 * MB);
    bf16* WvT  = (bf16*)(w + 22 * MB);
    bf16* WsT  = (bf16*)(w + 24 * MB);
    bf16* HpA  = (bf16*)(w + 18 * MB);           // [18,24) after merged GEMM
    bf16* gnwb = (bf16*)(w + 24 * MB + 524288);  // smalls [24.5,25)
    bf16* qwb  = (bf16*)(w + 24 * MB + 532480);
    bf16* kwb  = (bf16*)(w + 24 * MB + 540672);
    bf16* vwb  = (bf16*)(w + 24 * MB + 548864);
    int*  flagp= (int*) (w + 24 * MB + 565248);
    bf16* qkpre= (bf16*)(w + 25 * MB);           // [25,41) -> Svp after convs
    bf16* Svp  = (bf16*)(w + 25 * MB);
    bf16* ETb  = (bf16*)(w + 41 * MB);           // [41,45)
    bf16* vpre = (bf16*)(w + 45 * MB);           // [45,61) -> Qb/KTb after conv_v
    bf16* Qb   = (bf16*)(w + 45 * MB);           // [45,53)
    bf16* KTb  = (bf16*)(w + 53 * MB);           // [53,61)
    float* Ccp = (float*)(w + 61 * MB);          // [61,61.25)
    bf16* HpB  = (bf16*)(w + 61 * MB + 262144);  // [61.25,63.25)
    bf16* VT   = (bf16*)d_out;                   // d_out[0,16MB)
    bf16* gate = (bf16*)d_out + 8 * 1024 * 1024; // d_out[16,32MB)

    dim3 blk(256);
    probe_dtype_kernel<<<1, blk, 0, stream>>>(d_in[0], flagp);
    convert_fused<<<9281, blk, 0, stream>>>(d_in[0],
                                            d_in[1], d_in[2], d_in[3], d_in[4],
                                            d_in[5], d_in[6],
                                            d_in[7], d_in[8], d_in[9], d_in[10],
                                            Xb, WallT, WkT, WvT, WsT, WgT, WoT,
                                            qwb, kwb, vwb, gnwb, flagp);
    // merged projection GEMM (256^2 tile, 4-phase): 416 = 8 XCD x 52.
    gemm256_8p<4, 8><<<416, dim3(512), 0, stream>>>(Xb, WallT, qkpre, ETb, gate,
                                                    vpre, flagp);
    // conv_v FIRST (reads vpre); then conv_qk (Qb/KTb alias vpre).
    conv_v_kernel<<<2048, blk, 0, stream>>>(vpre, vwb, VT);
    conv_qk_kernel<<<1024, blk, 0, stream>>>(qkpre, qwb, kwb, Qb, KTb);
    tile_state_kernel<<<1280, blk, 0, stream>>>(ETb, KTb, VT, Svp, HpA, HpB, Ccp);
    prefix_state_kernel<<<1536, blk, 0, stream>>>(Svp, HpA, HpB);
    attn12_mfma<<<dim3(16, 32), blk, 0, stream>>>(Qb, KTb, ETb, Ccp, HpA, HpB,
                                                  Svp, VT, gate, gnwb, OVb);
    // output projection: 128x256 tiles -> 256 blocks = one full round.
    gemm256_8p<3, 4><<<256, dim3(512), 0, stream>>>(OVb, WoT, d_out, nullptr,
                                                    nullptr, nullptr, flagp);
}

// Round 11
// 344.329 us; speedup vs baseline: 1.0739x; 1.0234x over previous
//
#include <hip/hip_runtime.h>
#include <hip/hip_bf16.h>
#include <math.h>

typedef __hip_bfloat16 bf16;
typedef short s8v __attribute__((ext_vector_type(8)));
typedef short s4v __attribute__((ext_vector_type(4)));
typedef float f4v __attribute__((ext_vector_type(4)));

__device__ __forceinline__ float b2f(bf16 x) { return __bfloat162float(x); }
__device__ __forceinline__ bf16 f2b(float x) { return __float2bfloat16(x); }
__device__ __forceinline__ f4v mfma16(s8v a, s8v b, f4v c) {
    return __builtin_amdgcn_mfma_f32_16x16x32_bf16(a, b, c, 0, 0, 0);
}
__device__ __forceinline__ void async16(const bf16* g, bf16* l) {
    __builtin_amdgcn_global_load_lds(
        (const __attribute__((address_space(1))) void*)g,
        (__attribute__((address_space(3))) void*)l, 16, 0, 0);
}

constexpr int Bn = 4, Tn = 2048, Dn = 1024, KDn = 512, VDn = 1024;
constexpr int Hn = 4, Mn = 64, HKn = 128, HVn = 256;
constexpr int BT = Bn * Tn;

// ---------------------------------------------------------------------------
__global__ __launch_bounds__(256) void probe_dtype_kernel(
    const void* __restrict__ x, int* __restrict__ flag)
{
    const bf16* xb = (const bf16*)x;
    float mx = 0.f;
    for (int i = threadIdx.x; i < 4096; i += 256) {
        float v = fabsf(b2f(xb[i]));
        if (isnan(v)) v = 1e30f;
        mx = fmaxf(mx, v);
    }
    __shared__ float red[256];
    red[threadIdx.x] = mx;
    __syncthreads();
    for (int s = 128; s > 0; s >>= 1) {
        if (threadIdx.x < s) red[threadIdx.x] = fmaxf(red[threadIdx.x], red[threadIdx.x + s]);
        __syncthreads();
    }
    if (threadIdx.x == 0) flag[0] = (red[0] > 1e6f) ? 1 : 0;
}

// ---------------------------------------------------------------------------
// All input conversions in ONE launch (unchanged).
// ---------------------------------------------------------------------------
__global__ __launch_bounds__(256) void convert_fused(
    const void* __restrict__ x,
    const void* s0, const void* s1, const void* s2, const void* s3,
    const void* s4, const void* s5,
    const void* sq, const void* sk, const void* sv, const void* sg,
    bf16* __restrict__ Xb,
    bf16* d0, bf16* d1, bf16* d2, bf16* d3, bf16* d4, bf16* d5,
    bf16* __restrict__ qd, bf16* __restrict__ kd,
    bf16* __restrict__ vd, bf16* __restrict__ gd,
    const int* __restrict__ flag)
{
    __shared__ bf16 tile[64 * 72];
    const int nb = blockIdx.x, tid = threadIdx.x;
    const int is32 = flag[0];
    if (nb < 8192) {
        int i0 = (nb * 256 + tid) * 4;
#pragma unroll
        for (int j = 0; j < 4; j++) {
            int i = i0 + j;
            if (i < BT * Dn)
                Xb[i] = is32 ? f2b(((const float*)x)[i]) : ((const bf16*)x)[i];
        }
    } else if (nb == 8192) {
        for (int i = tid; i < 8448; i += 256) {
            const void* s; bf16* d; int l;
            if (i < 2048)      { s = sq; d = qd; l = i; }
            else if (i < 4096) { s = sk; d = kd; l = i - 2048; }
            else if (i < 8192) { s = sv; d = vd; l = i - 4096; }
            else               { s = sg; d = gd; l = i - 8192; }
            d[l] = is32 ? f2b(((const float*)s)[l]) : ((const bf16*)s)[l];
        }
    } else {
        int nb2 = nb - 8193;
        const void* src; bf16* dst; int K, N, loc;
        if (nb2 < 128)       { src = s0; dst = d0; K = 1024; N = 512;  loc = nb2; }
        else if (nb2 < 256)  { src = s1; dst = d1; K = 1024; N = 512;  loc = nb2 - 128; }
        else if (nb2 < 512)  { src = s2; dst = d2; K = 1024; N = 1024; loc = nb2 - 256; }
        else if (nb2 < 576)  { src = s3; dst = d3; K = 1024; N = 256;  loc = nb2 - 512; }
        else if (nb2 < 832)  { src = s4; dst = d4; K = 1024; N = 1024; loc = nb2 - 576; }
        else                 { src = s5; dst = d5; K = 1024; N = 1024; loc = nb2 - 832; }
        int nt = N >> 6;
        int n0 = (loc % nt) * 64, k0 = (loc / nt) * 64;
        int r = tid >> 2, seg = (tid & 3) * 16;
#pragma unroll
        for (int i = 0; i < 16; i++) {
            size_t gi = (size_t)(k0 + r) * N + n0 + seg + i;
            float v = is32 ? ((const float*)src)[gi] : b2f(((const bf16*)src)[gi]);
            tile[r * 72 + seg + i] = f2b(v);
        }
        __syncthreads();
        bf16 tmp[16];
#pragma unroll
        for (int i = 0; i < 16; i++) tmp[i] = tile[(seg + i) * 72 + r];
        size_t o = (size_t)(n0 + r) * K + k0 + seg;
        *(s8v*)&dst[o] = *(s8v*)&tmp[0];
        *(s8v*)&dst[o + 8] = *(s8v*)&tmp[8];
    }
}

// ---------------------------------------------------------------------------
// BM x 256 tile GEMM (BM = MF*32), m201-style 4-phase schedule.
// Verified r6-r10; GOLDEN, do not touch. Direct-store epilogue (r9 lesson).
// ---------------------------------------------------------------------------
template <int EP, int MF>
__global__ __launch_bounds__(512, 2) void gemm256_8p(
    const bf16* __restrict__ A, const bf16* __restrict__ Bt,
    void* __restrict__ Cout, bf16* __restrict__ ETout,
    bf16* __restrict__ aux1, bf16* __restrict__ aux2,
    const int* __restrict__ flag)
{
    constexpr int BM = MF * 32;          // 256 or 128
    constexpr int ASZ = BM * 64;         // A buffer elems (16384 / 8192)
    constexpr int PM = MF / 4;           // m-frags per phase (2 / 1)
    __shared__ bf16 lds[2 * ASZ + 2 * 16384];
    constexpr int K = 1024, NT = 16;
    const int tid = threadIdx.x;
    const int w8 = tid >> 6, lane = tid & 63;
    const int l16 = lane & 15, q2 = lane >> 4;
    const int wr = w8 >> 2, wc = w8 & 3;

    const int bid = blockIdx.x;
    const int xcd = bid & 7, ii = bid >> 3;
    int bx, by;
    if (EP == 4) {
        if (ii < 48) {
            int sc = ii >> 3, rem = ii & 7;
            bx = sc * 2 + (rem & 1);
            by = xcd * 4 + (rem >> 1);
        } else {
            bx = 12;
            by = xcd * 4 + (ii - 48);
        }
    } else {
        bx = ii >> 3;            // 0..3
        by = xcd * 8 + (ii & 7); // 0..63
    }

    const int srow = tid >> 3;
    const int sslot = (tid & 7) ^ (srow & 7);
    const bf16* gA0 = A + (size_t)(by * BM + srow) * K + sslot * 8;
    const bf16* gB0 = Bt + (size_t)(bx * 256 + srow) * K + sslot * 8;
    const int dOff = w8 * 512;

    const int sz0 = ((q2 ^ (l16 & 7))) * 8;
    const int sz1 = (((q2 ^ 4) ^ (l16 & 7))) * 8;
    const int rowA = (wr * (MF * 16) + l16) * 64;

    f4v acc[MF][4];
    f4v z = {0.f, 0.f, 0.f, 0.f};
#pragma unroll
    for (int i = 0; i < MF; i++)
#pragma unroll
        for (int j = 0; j < 4; j++) acc[i][j] = z;

    // prologue: B(0) 4, A(0) MF/2, B(1) 4
#pragma unroll
    for (int g = 0; g < 4; ++g)
        async16(gB0 + (size_t)g * 64 * K, &lds[2 * ASZ] + g * 4096 + dOff);
#pragma unroll
    for (int g = 0; g < MF / 2; ++g)
        async16(gA0 + (size_t)g * 64 * K, &lds[0] + g * 4096 + dOff);
#pragma unroll
    for (int g = 0; g < 4; ++g)
        async16(gB0 + (size_t)g * 64 * K + 64, &lds[2 * ASZ + 16384] + g * 4096 + dOff);
    asm volatile("s_waitcnt vmcnt(4)" ::: "memory");
    __builtin_amdgcn_s_barrier();

    for (int t = 0; t < NT; ++t) {
        const int da = t & 1;
        const bf16* bufA = &lds[da * ASZ];
        const bf16* bufB = &lds[2 * ASZ + da * 16384];
        bf16* stA = &lds[(da ^ 1) * ASZ];
        bf16* stB = &lds[2 * ASZ + da * 16384];
        const int tA = (t + 1 < NT) ? (t + 1) : (NT - 1);
        const int tB = (t + 2 < NT) ? (t + 2) : (NT - 1);
        s8v breg[4][2];
#pragma unroll
        for (int q = 0; q < 4; ++q) {
            if (q == 0) {
#pragma unroll
                for (int ni = 0; ni < 4; ++ni) {
                    int rb = (wc * 64 + ni * 16 + l16) * 64;
                    breg[ni][0] = *(const s8v*)(bufB + rb + sz0);
                    breg[ni][1] = *(const s8v*)(bufB + rb + sz1);
                }
            }
            s8v aq[PM][2];
#pragma unroll
            for (int m = 0; m < PM; ++m) {
                int ra = rowA + (q * PM + m) * 1024;
                aq[m][0] = *(const s8v*)(bufA + ra + sz0);
                aq[m][1] = *(const s8v*)(bufA + ra + sz1);
            }
            if (q == 0) {
#pragma unroll
                for (int g = 0; g < MF / 2; ++g)
                    async16(gA0 + (size_t)tA * 64 + (size_t)g * 64 * K,
                            stA + g * 4096 + dOff);
            } else if (q == 1) {
#pragma unroll
                for (int g = 0; g < 2; ++g)
                    async16(gB0 + (size_t)tB * 64 + (size_t)g * 64 * K,
                            stB + g * 4096 + dOff);
            } else if (q == 2) {
#pragma unroll
                for (int g = 2; g < 4; ++g)
                    async16(gB0 + (size_t)tB * 64 + (size_t)g * 64 * K,
                            stB + g * 4096 + dOff);
            } else {
                asm volatile("s_waitcnt vmcnt(4)" ::: "memory");
            }
            __builtin_amdgcn_s_barrier();
            asm volatile("s_waitcnt lgkmcnt(0)" ::: "memory");
            __builtin_amdgcn_sched_barrier(0);
            __builtin_amdgcn_s_setprio(1);
#pragma unroll
            for (int kq = 0; kq < 2; ++kq)
#pragma unroll
                for (int m = 0; m < PM; ++m)
#pragma unroll
                    for (int ni = 0; ni < 4; ++ni)
                        acc[q * PM + m][ni] =
                            mfma16(aq[m][kq], breg[ni][kq], acc[q * PM + m][ni]);
            __builtin_amdgcn_s_setprio(0);
            __builtin_amdgcn_s_barrier();
        }
    }
    asm volatile("s_waitcnt vmcnt(0)" ::: "memory");

    const int row0 = by * BM + wr * (MF * 16) + q2 * 4;
    const int col0 = bx * 256 + wc * 64 + l16;
    if (EP == 4) {
        if (bx < 12) {
            bf16* dst = (bx < 4) ? (bf16*)Cout : (bx < 8 ? aux1 : aux2);
            const int cb = (bx < 4) ? 0 : (bx < 8 ? 1024 : 2048);
#pragma unroll
            for (int mi = 0; mi < MF; ++mi)
#pragma unroll
                for (int ni = 0; ni < 4; ++ni)
#pragma unroll
                    for (int r = 0; r < 4; ++r) {
                        int row = row0 + mi * 16 + r;
                        int col = col0 + ni * 16 - cb;
                        dst[(size_t)row * 1024 + col] = f2b(acc[mi][ni][r]);
                    }
        } else {
#pragma unroll
            for (int mi = 0; mi < MF; ++mi)
#pragma unroll
                for (int ni = 0; ni < 4; ++ni)
#pragma unroll
                    for (int r = 0; r < 4; ++r) {
                        int row = row0 + mi * 16 + r;
                        int c = wc * 64 + ni * 16 + l16;
                        float v = acc[mi][ni][r];
                        float cl = fminf(32.f, fmaxf(-32.f, v));
                        int b_ = row >> 11, t_ = row & 2047;
                        int h_ = c >> 6, m_ = c & 63;
                        ETout[((size_t)((b_ * 4 + h_) * 64 + m_)) * 2048 + t_]
                            = f2b(expf(cl));
                    }
        }
    } else {
        const int dyn = flag[0];
#pragma unroll
        for (int mi = 0; mi < MF; ++mi)
#pragma unroll
            for (int ni = 0; ni < 4; ++ni)
#pragma unroll
                for (int r = 0; r < 4; ++r) {
                    int row = row0 + mi * 16 + r;
                    int col = col0 + ni * 16;
                    float v = acc[mi][ni][r];
                    size_t idx = (size_t)row * 1024 + col;
                    if (dyn) ((float*)Cout)[idx] = v;
                    else ((bf16*)Cout)[idx] = f2b(v);
                }
    }
}

// ---------------------------------------------------------------------------
// Merged conv kernel (r9-verified structure): nb<2048 -> v (conv+silu -> VT,
// transposed); [2048,2560) -> q (vectorized conv+silu+rope -> Qb);
// [2560,3072) -> k (conv+silu+rope -> KTb, transposed).
// No aliasing: Qb/KTb live over dead Xb; vpre untouched by qk branches.
// __expf for silu (native v_exp_f32; error negligible vs bf16 rounding).
// ---------------------------------------------------------------------------
__global__ __launch_bounds__(256) void conv_all2_kernel(
    const bf16* __restrict__ qkpre, const bf16* __restrict__ vpre,
    const bf16* __restrict__ qw, const bf16* __restrict__ kw,
    const bf16* __restrict__ vw,
    bf16* __restrict__ Qb, bf16* __restrict__ KT, bf16* __restrict__ VT)
{
    __shared__ bf16 tile[128 * 72];
    const int nb = blockIdx.x, tid = threadIdx.x;
    if (nb < 2048) {
        int c0 = (nb & 15) * 64, t0 = ((nb >> 4) & 31) * 64, b = nb >> 9;
        int row = tid >> 2, seg = (tid & 3) * 16;
        float y[16];
#pragma unroll
        for (int i = 0; i < 16; i++) y[i] = 0.f;
#pragma unroll
        for (int j = 0; j < 4; j++) {
            int tt = t0 + row - 3 + j;
            if (tt >= 0) {
                const bf16* p = &vpre[(size_t)(b * Tn + tt) * VDn + c0 + seg];
#pragma unroll
                for (int i = 0; i < 16; i++)
                    y[i] += b2f(p[i]) * b2f(vw[(c0 + seg + i) * 4 + j]);
            }
        }
#pragma unroll
        for (int i = 0; i < 16; i++) {
            float v = y[i] / (1.f + __expf(-y[i]));
            tile[row * 72 + seg + i] = f2b(v);
        }
        __syncthreads();
        bf16 tmp[16];
#pragma unroll
        for (int i = 0; i < 16; i++) tmp[i] = tile[(seg + i) * 72 + row];
        size_t o = (size_t)(b * 1024 + c0 + row) * 2048 + t0 + seg;
        *(s8v*)&VT[o] = *(s8v*)&tmp[0];
        *(s8v*)&VT[o + 8] = *(s8v*)&tmp[8];
    } else if (nb < 2560) {
        const int nq = nb - 2048;
        const int h = nq & 3, tt = (nq >> 2) & 31, b = nq >> 7;
        const int row = tid >> 2, seg = (tid & 3) * 16;
        const int t = tt * 64 + row;
        const int clo = h * 128 + seg;
        float ylo[16], yhi[16];
#pragma unroll
        for (int i = 0; i < 16; i++) { ylo[i] = 0.f; yhi[i] = 0.f; }
        alignas(16) bf16 wlo[64], whi[64];
#pragma unroll
        for (int c = 0; c < 8; c++) {
            *(s8v*)&wlo[c * 8] = *(const s8v*)&qw[clo * 4 + c * 8];
            *(s8v*)&whi[c * 8] = *(const s8v*)&qw[(clo + 64) * 4 + c * 8];
        }
#pragma unroll
        for (int j = 0; j < 4; j++) {
            int ts = t - 3 + j;
            if (ts >= 0) {
                const bf16* p = &qkpre[(size_t)(b * Tn + ts) * 1024 + clo];
                alignas(16) bf16 xl[16], xh[16];
                *(s8v*)&xl[0] = *(const s8v*)p;
                *(s8v*)&xl[8] = *(const s8v*)(p + 8);
                *(s8v*)&xh[0] = *(const s8v*)(p + 64);
                *(s8v*)&xh[8] = *(const s8v*)(p + 72);
#pragma unroll
                for (int i = 0; i < 16; i++) {
                    ylo[i] += b2f(xl[i]) * b2f(wlo[i * 4 + j]);
                    yhi[i] += b2f(xh[i]) * b2f(whi[i * 4 + j]);
                }
            }
        }
        alignas(16) bf16 olo[16], ohi[16];
#pragma unroll
        for (int i = 0; i < 16; i++) {
            float yl = ylo[i] / (1.f + __expf(-ylo[i]));
            float yh = yhi[i] / (1.f + __expf(-yhi[i]));
            float invf = exp2f(-(float)(seg + i) * 0.2076205059304601f);
            float th = (float)t * invf;
            float c = cosf(th), s = sinf(th);
            olo[i] = f2b(yl * c - yh * s);
            ohi[i] = f2b(yh * c + yl * s);
        }
        size_t rb = (size_t)(b * Tn + t) * KDn + clo;
        *(s8v*)&Qb[rb] = *(s8v*)&olo[0];
        *(s8v*)&Qb[rb + 8] = *(s8v*)&olo[8];
        *(s8v*)&Qb[rb + 64] = *(s8v*)&ohi[0];
        *(s8v*)&Qb[rb + 72] = *(s8v*)&ohi[8];
    } else {
        int r = nb - 2560;
        const int tt = r & 31, h = (r >> 5) & 3, b = r >> 7;
        const int dp = tid >> 2, tq = tid & 3;
        const int clo = 512 + h * 128 + dp, chi = clo + 64;
        const float w0l = b2f(kw[(h * 128 + dp) * 4 + 0]), w1l = b2f(kw[(h * 128 + dp) * 4 + 1]),
                    w2l = b2f(kw[(h * 128 + dp) * 4 + 2]), w3l = b2f(kw[(h * 128 + dp) * 4 + 3]);
        const float w0h = b2f(kw[(h * 128 + dp + 64) * 4 + 0]), w1h = b2f(kw[(h * 128 + dp + 64) * 4 + 1]),
                    w2h = b2f(kw[(h * 128 + dp + 64) * 4 + 2]), w3h = b2f(kw[(h * 128 + dp + 64) * 4 + 3]);
        const float invf = exp2f(-(float)dp * 0.2076205059304601f);
        float l0 = 0.f, l1 = 0.f, l2 = 0.f, h0 = 0.f, h1 = 0.f, h2 = 0.f;
        int tg0 = tt * 64 + tq * 16;
#pragma unroll
        for (int p = 0; p < 3; p++) {
            int tg = tg0 - 3 + p;
            float xl = 0.f, xh = 0.f;
            if (tg >= 0) {
                size_t rb = (size_t)(b * Tn + tg) * 1024;
                xl = b2f(qkpre[rb + clo]);
                xh = b2f(qkpre[rb + chi]);
            }
            l0 = l1; l1 = l2; l2 = xl;
            h0 = h1; h1 = h2; h2 = xh;
        }
        for (int i = 0; i < 16; i++) {
            int tg = tg0 + i;
            size_t rb = (size_t)(b * Tn + tg) * 1024;
            float xl = b2f(qkpre[rb + clo]);
            float xh = b2f(qkpre[rb + chi]);
            float ylo = l0 * w0l + l1 * w1l + l2 * w2l + xl * w3l;
            float yhi = h0 * w0h + h1 * w1h + h2 * w2h + xh * w3h;
            l0 = l1; l1 = l2; l2 = xl;
            h0 = h1; h1 = h2; h2 = xh;
            ylo = ylo / (1.f + __expf(-ylo));
            yhi = yhi / (1.f + __expf(-yhi));
            float th = (float)tg * invf;
            float c = cosf(th), s = sinf(th);
            int tl = tq * 16 + i;
            tile[dp * 72 + tl] = f2b(ylo * c - yhi * s);
            tile[(dp + 64) * 72 + tl] = f2b(yhi * c + ylo * s);
        }
        __syncthreads();
#pragma unroll
        for (int c = 0; c < 4; c++) {
            int idx = c * 256 + tid;
            int ch = idx >> 3, t8 = (idx & 7) * 8;
            s8v v = *(s8v*)&tile[ch * 72 + t8];
            *(s8v*)&KT[((size_t)((b * 4 + h) * 128 + ch)) * 2048 + tt * 64 + t8] = v;
        }
    }
}

// ---------------------------------------------------------------------------
// Phase A + cumsum merged (unchanged).
// ---------------------------------------------------------------------------
__global__ __launch_bounds__(256) void tile_state_kernel(
    const bf16* __restrict__ ET, const bf16* __restrict__ KT,
    const bf16* __restrict__ VT,
    bf16* __restrict__ Svp, bf16* __restrict__ HpA, bf16* __restrict__ HpB,
    float* __restrict__ Ccp)
{
    const int tid = threadIdx.x;
    const int w = tid >> 6, lane = tid & 63;
    const int l16 = lane & 15, q = lane >> 4;
    f4v z = {0.f, 0.f, 0.f, 0.f};
    if (blockIdx.x < 512) {
        const int bh = blockIdx.x >> 5, j = blockIdx.x & 31;
        const int b = bh >> 2, h = bh & 3;
        const int j64 = j * 64;
        f4v acc[4][4];
#pragma unroll
        for (int i = 0; i < 4; i++)
#pragma unroll
            for (int jj = 0; jj < 4; jj++) acc[i][jj] = z;
#pragma unroll
        for (int kc = 0; kc < 2; kc++) {
            s8v va[4], eb[4];
#pragma unroll
            for (int vf = 0; vf < 4; vf++)
                va[vf] = *(const s8v*)(VT + (size_t)(b * 1024 + h * 256 + w * 64 + vf * 16 + l16) * 2048
                                       + j64 + kc * 32 + q * 8);
#pragma unroll
            for (int mf = 0; mf < 4; mf++)
                eb[mf] = *(const s8v*)(ET + (size_t)(bh * 64 + mf * 16 + l16) * 2048
                                       + j64 + kc * 32 + q * 8);
#pragma unroll
            for (int vf = 0; vf < 4; vf++)
#pragma unroll
                for (int mf = 0; mf < 4; mf++)
                    acc[vf][mf] = mfma16(va[vf], eb[mf], acc[vf][mf]);
        }
#pragma unroll
        for (int vf = 0; vf < 4; vf++)
#pragma unroll
            for (int mf = 0; mf < 4; mf++)
#pragma unroll
                for (int r = 0; r < 4; r++)
                    Svp[((size_t)((bh * 32 + j) * 256 + w * 64 + vf * 16 + q * 4 + r)) * 64
                        + mf * 16 + l16] = f2b(acc[vf][mf][r]);
    } else if (blockIdx.x < 1024) {
        const int idx = blockIdx.x - 512;
        const int bh = idx >> 5, j = idx & 31;
        const int j64 = j * 64;
        bf16* hp = (bh < 12) ? (HpA + (size_t)bh * 262144)
                             : (HpB + (size_t)(bh - 12) * 262144);
        f4v acc[8];
#pragma unroll
        for (int i = 0; i < 8; i++) acc[i] = z;
#pragma unroll
        for (int kc = 0; kc < 2; kc++) {
            s8v ea = *(const s8v*)(ET + (size_t)(bh * 64 + w * 16 + l16) * 2048
                                   + j64 + kc * 32 + q * 8);
#pragma unroll
            for (int kf = 0; kf < 8; kf++) {
                s8v kb = *(const s8v*)(KT + (size_t)(bh * 128 + kf * 16 + l16) * 2048
                                       + j64 + kc * 32 + q * 8);
                acc[kf] = mfma16(ea, kb, acc[kf]);
            }
        }
#pragma unroll
        for (int kf = 0; kf < 8; kf++)
#pragma unroll
            for (int r = 0; r < 4; r++)
                hp[((size_t)(j64 + w * 16 + q * 4 + r)) * 128 + kf * 16 + l16]
                    = f2b(acc[kf][r]);
    } else {
        int row = (blockIdx.x - 1024) * 4 + w;
        int b = row >> 8, hm = row & 255;
        const bf16* src = ET + (size_t)row * 2048;
        float run = 0.f;
        for (int ch = 0; ch < 32; ch++) {
            if (lane == 0) Ccp[(size_t)(b * 32 + ch) * 256 + hm] = run;
            float v = b2f(src[ch * 64 + lane]);
#pragma unroll
            for (int off = 1; off < 64; off <<= 1) {
                float o = __shfl_up(v, off, 64);
                if (lane >= off) v += o;
            }
            run += __shfl(v, 63, 64);
        }
    }
}

// ---------------------------------------------------------------------------
// Phase B: in-place exclusive prefix over j (unchanged).
// ---------------------------------------------------------------------------
__global__ __launch_bounds__(256) void prefix_state_kernel(
    bf16* __restrict__ Svp, bf16* __restrict__ HpA, bf16* __restrict__ HpB)
{
    if (blockIdx.x < 1024) {
        int gid = blockIdx.x * 256 + threadIdx.x;
        int bh = gid >> 14, e = gid & 16383;
        bf16* p = Svp + (size_t)bh * 524288 + e;
        float run = 0.f;
#pragma unroll 4
        for (int j = 0; j < 32; j++) {
            float x = b2f(p[(size_t)j * 16384]);
            p[(size_t)j * 16384] = f2b(run);
            run += x;
        }
    } else {
        int gid = (blockIdx.x - 1024) * 256 + threadIdx.x;
        int bh = gid >> 13, e = gid & 8191;
        bf16* hp = ((bh < 12) ? (HpA + (size_t)bh * 262144)
                              : (HpB + (size_t)(bh - 12) * 262144)) + e;
        float run = 0.f;
#pragma unroll 4
        for (int j = 0; j < 32; j++) {
            float x = b2f(hp[(size_t)j * 8192]);
            hp[(size_t)j * 8192] = f2b(run);
            run += x;
        }
    }
}

// ---------------------------------------------------------------------------
// Fused attention. Changes vs r10: __expf for softmax exp + silu gate
// (native v_exp_f32), #pragma unroll on the cumsum scan loop (16
// independent per-row scan chains -> ILP hides shfl latency).
// ---------------------------------------------------------------------------
__global__ __launch_bounds__(256) void attn12_mfma(
    const bf16* __restrict__ Q, const bf16* __restrict__ KT,
    const bf16* __restrict__ ET, const float* __restrict__ Ccp,
    const bf16* __restrict__ HpA, const bf16* __restrict__ HpB,
    const bf16* __restrict__ Svp, const bf16* __restrict__ VT,
    const bf16* __restrict__ gate, const bf16* __restrict__ gn,
    bf16* __restrict__ OV)
{
    __shared__ char smem[53760];
    bf16*  Kloc = (bf16*)smem;
    float* Ot   = (float*)smem;
    bf16*  Sl   = (bf16*)(smem + 17408);
    bf16*  Ct   = (bf16*)(smem + 17408);
    bf16*  Etl  = (bf16*)(smem + 17408);
    float* okT  = (float*)(smem + 26624);
    bf16*  Pl   = (bf16*)(smem + 26624);
    bf16*  Ul   = (bf16*)(smem + 43264);
    float* swave= (float*)(smem + 52480);
    float* ssum = (float*)(smem + 53504);
    const int tid = threadIdx.x;
    const int w = tid >> 6, lane = tid & 63;
    const int l16 = lane & 15, q = lane >> 4;
    const int bh = blockIdx.x, b = bh >> 2, h = bh & 3;
    const int j = blockIdx.y, j64 = j * 64;
    f4v z = {0.f, 0.f, 0.f, 0.f};
    const bf16* hp = (bh < 12) ? (HpA + (size_t)bh * 262144)
                               : (HpB + (size_t)(bh - 12) * 262144);

#pragma unroll
    for (int c = 0; c < 4; c++) {
        int idx = c * 256 + tid;
        int kr = idx >> 3, t8 = (idx & 7) * 8;
        alignas(16) bf16 tmp[8];
        *(s8v*)tmp = *(const s8v*)&KT[((size_t)(bh * 128 + kr)) * 2048 + j64 + t8];
#pragma unroll
        for (int i = 0; i < 8; i++) Kloc[(t8 + i) * 136 + kr] = tmp[i];
    }
    const bf16* qrow = Q + (size_t)(b * 2048 + j64 + w * 16 + l16) * 512 + h * 128;
    s8v qa[4];
#pragma unroll
    for (int kc = 0; kc < 4; kc++) qa[kc] = *(const s8v*)(qrow + kc * 32 + q * 8);
    __syncthreads();
    {
        f4v sT[4];
#pragma unroll
        for (int fi = 0; fi < 4; fi++) sT[fi] = z;
#pragma unroll
        for (int kc = 0; kc < 4; kc++)
#pragma unroll
            for (int fi = 0; fi < 4; fi++) {
                s8v kb = *(s8v*)&Kloc[(fi * 16 + l16) * 136 + kc * 32 + q * 8];
                sT[fi] = mfma16(kb, qa[kc], sT[fi]);
            }
        const int tl = w * 16 + l16;
#pragma unroll
        for (int fi = 0; fi < 4; fi++) {
            alignas(8) bf16 pk[4];
#pragma unroll
            for (int r = 0; r < 4; r++) {
                int taul = fi * 16 + q * 4 + r;
                pk[r] = (taul <= tl) ? f2b(sT[fi][r]) : f2b(0.f);
            }
            *(s4v*)&Sl[tl * 72 + fi * 16 + q * 4] = *(s4v*)pk;
        }
    }
    __syncthreads();
    {
        f4v ok[4];
#pragma unroll
        for (int i = 0; i < 4; i++) ok[i] = z;
        const bf16* etrow = ET + (size_t)(bh * 64 + w * 16 + l16) * 2048 + j64;
#pragma unroll
        for (int kc = 0; kc < 2; kc++) {
            s8v ea = *(const s8v*)(etrow + kc * 32 + q * 8);
#pragma unroll
            for (int tf = 0; tf < 4; tf++) {
                s8v sb = *(s8v*)&Sl[(tf * 16 + l16) * 72 + kc * 32 + q * 8];
                ok[tf] = mfma16(ea, sb, ok[tf]);
            }
        }
        const bf16* hrow = hp + (size_t)(j64 + w * 16 + l16) * 128;
#pragma unroll
        for (int kc = 0; kc < 4; kc++) {
            s8v ha = *(const s8v*)(hrow + kc * 32 + q * 8);
#pragma unroll
            for (int tf = 0; tf < 4; tf++) {
                s8v qb = *(const s8v*)(Q + (size_t)(b * 2048 + j64 + tf * 16 + l16) * 512
                                       + h * 128 + kc * 32 + q * 8);
                ok[tf] = mfma16(ha, qb, ok[tf]);
            }
        }
#pragma unroll
        for (int tf = 0; tf < 4; tf++)
#pragma unroll
            for (int r = 0; r < 4; r++)
                okT[(w * 16 + q * 4 + r) * 65 + tf * 16 + l16] = ok[tf][r];
    }
    __syncthreads();
#pragma unroll
    for (int mi = 0; mi < 16; mi++) {
        int m = w * 16 + mi;
        float v = b2f(ET[(size_t)(bh * 64 + m) * 2048 + j64 + lane]);
#pragma unroll
        for (int off = 1; off < 64; off <<= 1) {
            float o = __shfl_up(v, off, 64);
            if (lane >= off) v += o;
        }
        float c0 = Ccp[(size_t)(b * 32 + j) * 256 + h * 64 + m];
        Ct[m * 72 + lane] = f2b(c0 + v);
    }
    __syncthreads();
    {
        const float scale = 0.08838834764831845f;
        float mx = -1e30f;
#pragma unroll
        for (int mi = 0; mi < 16; mi++) {
            int m = w * 16 + mi;
            float c = b2f(Ct[m * 72 + lane]);
            float v = okT[m * 65 + lane] * scale / c;
            okT[m * 65 + lane] = v;
            mx = fmaxf(mx, v);
        }
        swave[w * 64 + lane] = mx;
        __syncthreads();
        mx = fmaxf(fmaxf(swave[lane], swave[64 + lane]),
                   fmaxf(swave[128 + lane], swave[192 + lane]));
        float sum = 0.f;
#pragma unroll
        for (int mi = 0; mi < 16; mi++) {
            int m = w * 16 + mi;
            float e = __expf(okT[m * 65 + lane] - mx);
            okT[m * 65 + lane] = e;
            sum += e;
        }
        __syncthreads();
        swave[w * 64 + lane] = sum;
        __syncthreads();
        float inv = 1.f / (swave[lane] + swave[64 + lane]
                           + swave[128 + lane] + swave[192 + lane]);
#pragma unroll
        for (int mi = 0; mi < 16; mi++) {
            int m = w * 16 + mi;
            float c = b2f(Ct[m * 72 + lane]);
            Ul[lane * 72 + m] = f2b(okT[m * 65 + lane] * inv / c);
        }
    }
    __syncthreads();
#pragma unroll
    for (int c = 0; c < 2; c++) {
        int idx = c * 256 + tid;
        int mr = idx >> 3, t8 = (idx & 7) * 8;
        alignas(16) bf16 tmp[8];
        *(s8v*)tmp = *(const s8v*)&ET[(size_t)(bh * 64 + mr) * 2048 + j64 + t8];
#pragma unroll
        for (int i = 0; i < 8; i++) Etl[(t8 + i) * 72 + mr] = tmp[i];
    }
    __syncthreads();
    {
        s8v ub[2];
#pragma unroll
        for (int kc = 0; kc < 2; kc++)
            ub[kc] = *(s8v*)&Ul[(w * 16 + l16) * 72 + kc * 32 + q * 8];
        f4v pT[4];
#pragma unroll
        for (int fi = 0; fi < 4; fi++) pT[fi] = z;
#pragma unroll
        for (int kc = 0; kc < 2; kc++)
#pragma unroll
            for (int fi = 0; fi < 4; fi++) {
                s8v eb = *(s8v*)&Etl[(fi * 16 + l16) * 72 + kc * 32 + q * 8];
                pT[fi] = mfma16(eb, ub[kc], pT[fi]);
            }
        const int tl = w * 16 + l16;
#pragma unroll
        for (int fi = 0; fi < 4; fi++) {
            alignas(8) bf16 pk[4];
#pragma unroll
            for (int r = 0; r < 4; r++) {
                int taul = fi * 16 + q * 4 + r;
                pk[r] = (taul <= tl) ? f2b(pT[fi][r]) : f2b(0.f);
            }
            *(s4v*)&Pl[tl * 72 + fi * 16 + q * 4] = *(s4v*)pk;
        }
    }
    __syncthreads();
    f4v oacc[4][4];
#pragma unroll
    for (int zc = 0; zc < 4; zc++)
#pragma unroll
        for (int i = 0; i < 4; i++) oacc[zc][i] = z;
    {
        const bf16* vtrow = VT + (size_t)(b * 1024 + h * 256 + w * 16 + l16) * 2048 + j64;
        const bf16* svrow = Svp + (size_t)((bh * 32 + j) * 256 + w * 16 + l16) * 64;
#pragma unroll
        for (int kc = 0; kc < 2; kc++) {
            s8v pb[4], ub2[4];
#pragma unroll
            for (int tf = 0; tf < 4; tf++) {
                pb[tf] = *(s8v*)&Pl[(tf * 16 + l16) * 72 + kc * 32 + q * 8];
                ub2[tf] = *(s8v*)&Ul[(tf * 16 + l16) * 72 + kc * 32 + q * 8];
            }
#pragma unroll
            for (int zc = 0; zc < 4; zc++) {
                s8v vt = *(const s8v*)(vtrow + (size_t)(zc * 64) * 2048 + kc * 32 + q * 8);
                s8v sv = *(const s8v*)(svrow + (size_t)(zc * 64) * 64 + kc * 32 + q * 8);
#pragma unroll
                for (int tf = 0; tf < 4; tf++) {
                    oacc[zc][tf] = mfma16(vt, pb[tf], oacc[zc][tf]);
                    oacc[zc][tf] = mfma16(sv, ub2[tf], oacc[zc][tf]);
                }
            }
        }
    }
    float part[4] = {0.f, 0.f, 0.f, 0.f};
#pragma unroll
    for (int zc = 0; zc < 4; zc++)
#pragma unroll
        for (int tf = 0; tf < 4; tf++)
#pragma unroll
            for (int r = 0; r < 4; r++)
                part[tf] += oacc[zc][tf][r] * oacc[zc][tf][r];
#pragma unroll
    for (int tf = 0; tf < 4; tf++) {
        part[tf] += __shfl_xor(part[tf], 16, 64);
        part[tf] += __shfl_xor(part[tf], 32, 64);
    }
    if (q == 0) {
#pragma unroll
        for (int tf = 0; tf < 4; tf++) swave[w * 64 + tf * 16 + l16] = part[tf];
    }
    const int trow = tid >> 2, vseg = (tid & 3) * 16;
    for (int zc = 0; zc < 4; zc++) {
#pragma unroll
        for (int tf = 0; tf < 4; tf++)
            *(f4v*)&Ot[(tf * 16 + l16) * 68 + w * 16 + q * 4] = oacc[zc][tf];
        __syncthreads();
        if (zc == 0) {
            if (tid < 64)
                ssum[tid] = rsqrtf((swave[tid] + swave[64 + tid] + swave[128 + tid]
                                    + swave[192 + tid]) * (1.0f / 256.0f) + 1e-5f);
            __syncthreads();
        }
        float rs = ssum[trow];
        size_t orow = (size_t)(b * 2048 + j64 + trow) * 1024 + h * 256 + zc * 64 + vseg;
        alignas(16) bf16 gh[16];
        *(s8v*)&gh[0] = *(const s8v*)&gate[orow];
        *(s8v*)&gh[8] = *(const s8v*)&gate[orow + 8];
        alignas(16) bf16 tmp[16];
#pragma unroll
        for (int i = 0; i < 16; i++) {
            float g = b2f(gh[i]);
            float sg = g / (1.f + __expf(-g));
            float val = Ot[trow * 68 + vseg + i] * rs * b2f(gn[zc * 64 + vseg + i]) * sg;
            tmp[i] = f2b(val);
        }
        *(s8v*)&OV[orow] = *(s8v*)&tmp[0];
        *(s8v*)&OV[orow + 8] = *(s8v*)&tmp[8];
        __syncthreads();
    }
}

// ---------------------------------------------------------------------------
extern "C" void kernel_launch(void* const* d_in, const int* in_sizes, int n_in,
                              void* d_out, int out_size, void* d_ws, size_t ws_size,
                              hipStream_t stream)
{
    constexpr size_t MB = 1u << 20;
    char* w = (char*)d_ws;
    bf16* Xb   = (bf16*)(w + 0);                 // [0,16) -> Qb/KTb after mproj
    bf16* Qb   = (bf16*)(w + 0);                 // [0,8)
    bf16* KTb  = (bf16*)(w + 8 * MB);            // [8,16)
    bf16* WoT  = (bf16*)(w + 16 * MB);           // [16,18)
    bf16* WallT= (bf16*)(w + 18 * MB);           // [18,24.5): WqkT|WgT|WvT|WsT
    bf16* WkT  = (bf16*)(w + 19 * MB);
    bf16* WgT  = (bf16*)(w + 20 * MB);
    bf16* WvT  = (bf16*)(w + 22 * MB);
    bf16* WsT  = (bf16*)(w + 24 * MB);
    bf16* HpA  = (bf16*)(w + 18 * MB);           // [18,24) after merged GEMM
    bf16* gnwb = (bf16*)(w + 24 * MB + 524288);  // smalls [24.5,25)
    bf16* qwb  = (bf16*)(w + 24 * MB + 532480);
    bf16* kwb  = (bf16*)(w + 24 * MB + 540672);
    bf16* vwb  = (bf16*)(w + 24 * MB + 548864);
    int*  flagp= (int*) (w + 24 * MB + 565248);
    bf16* qkpre= (bf16*)(w + 25 * MB);           // [25,41) -> Svp after convs
    bf16* Svp  = (bf16*)(w + 25 * MB);
    bf16* ETb  = (bf16*)(w + 41 * MB);           // [41,45)
    bf16* vpre = (bf16*)(w + 45 * MB);           // [45,61) -> OVb after convs
    bf16* OVb  = (bf16*)(w + 45 * MB);
    float* Ccp = (float*)(w + 61 * MB);          // [61,61.25)
    bf16* HpB  = (bf16*)(w + 61 * MB + 262144);  // [61.25,63.25)
    bf16* VT   = (bf16*)d_out;                   // d_out[0,16MB)
    bf16* gate = (bf16*)d_out + 8 * 1024 * 1024; // d_out[16,32MB)

    dim3 blk(256);
    probe_dtype_kernel<<<1, blk, 0, stream>>>(d_in[0], flagp);
    convert_fused<<<9281, blk, 0, stream>>>(d_in[0],
                                            d_in[1], d_in[2], d_in[3], d_in[4],
                                            d_in[5], d_in[6],
                                            d_in[7], d_in[8], d_in[9], d_in[10],
                                            Xb, WallT, WkT, WvT, WsT, WgT, WoT,
                                            qwb, kwb, vwb, gnwb, flagp);
    // merged projection GEMM (256^2 tile, 4-phase): 416 = 8 XCD x 52.
    gemm256_8p<4, 8><<<416, dim3(512), 0, stream>>>(Xb, WallT, qkpre, ETb, gate,
                                                    vpre, flagp);
    // all convs in one launch (no aliasing: Qb/KTb over dead Xb).
    conv_all2_kernel<<<3072, blk, 0, stream>>>(qkpre, vpre, qwb, kwb, vwb,
                                               Qb, KTb, VT);
    tile_state_kernel<<<1280, blk, 0, stream>>>(ETb, KTb, VT, Svp, HpA, HpB, Ccp);
    prefix_state_kernel<<<1536, blk, 0, stream>>>(Svp, HpA, HpB);
    // attn writes OVb over dead vpre region.
    attn12_mfma<<<dim3(16, 32), blk, 0, stream>>>(Qb, KTb, ETb, Ccp, HpA, HpB,
                                                  Svp, VT, gate, gnwb, OVb);
    // output projection: 128x256 tiles -> 256 blocks = one full round.
    gemm256_8p<3, 4><<<256, dim3(512), 0, stream>>>(OVb, WoT, d_out, nullptr,
                                                    nullptr, nullptr, flagp);
}